// Round 7
// baseline (1418.994 us; speedup 1.0000x reference)
//
#include <hip/hip_runtime.h>

#define NN 50000
#define NE 800000
#define CIN 128
#define HH 64
#define NCLS 40
#define NL 15
#define DTC 0.1f
#define LNEPS 1e-5f
#define NB_SCAN 196   // ceil(50000/256)

typedef float f32x2 __attribute__((ext_vector_type(2)));

// ---------------- bf16x2 / fp8x2 pack-unpack ----------------

__device__ inline unsigned pack_bf2(float x, float y) {
    unsigned ux = __float_as_uint(x);
    unsigned uy = __float_as_uint(y);
    ux = (ux + 0x7fffu + ((ux >> 16) & 1u)) >> 16;   // RNE
    uy = (uy + 0x7fffu + ((uy >> 16) & 1u)) >> 16;
    return ux | (uy << 16);
}
__device__ inline float2 unpack_bf2(unsigned p) {
    float2 r;
    r.x = __uint_as_float(p << 16);
    r.y = __uint_as_float(p & 0xffff0000u);
    return r;
}
__device__ inline unsigned short pack_fp8x2(float x, float y) {
    int r = __builtin_amdgcn_cvt_pk_fp8_f32(x, y, 0, false);
    return (unsigned short)(r & 0xffff);
}
__device__ inline float2 unpack_fp8x2(unsigned short p) {
    f32x2 v = __builtin_amdgcn_cvt_pk_f32_fp8((int)(unsigned)p, false);
    float2 r; r.x = v.x; r.y = v.y; return r;
}

// ---------------- degree / normalization precompute ----------------

__global__ __launch_bounds__(256) void k_deg(const int* __restrict__ dst, int* __restrict__ deg) {
    int e = blockIdx.x * 256 + threadIdx.x;
    if (e < NE) atomicAdd(&deg[dst[e]], 1);
}

__global__ __launch_bounds__(256) void k_scan1(const int* __restrict__ deg, int* __restrict__ rp,
                                               int* __restrict__ bsum, float* __restrict__ dinv) {
    int i = blockIdx.x * 256 + threadIdx.x;
    int v = (i < NN) ? deg[i] : 0;
    if (i < NN) dinv[i] = rsqrtf(fmaxf((float)v, 1.0f));
    int lane = threadIdx.x & 63, wid = threadIdx.x >> 6;
    int inc = v;
#pragma unroll
    for (int d = 1; d < 64; d <<= 1) {
        int t = __shfl_up(inc, d, 64);
        if (lane >= d) inc += t;
    }
    __shared__ int wsum[4];
    if (lane == 63) wsum[wid] = inc;
    __syncthreads();
    int woff = 0;
#pragma unroll
    for (int w = 0; w < 4; ++w)
        if (w < wid) woff += wsum[w];
    if (i < NN) rp[i] = woff + inc - v;
    if (threadIdx.x == 255) bsum[blockIdx.x] = woff + inc;
}

__global__ __launch_bounds__(256) void k_scan2(const int* __restrict__ bsum, int* __restrict__ boff) {
    int t = threadIdx.x;
    int v = (t < NB_SCAN) ? bsum[t] : 0;
    int lane = t & 63, wid = t >> 6;
    int inc = v;
#pragma unroll
    for (int d = 1; d < 64; d <<= 1) {
        int tt = __shfl_up(inc, d, 64);
        if (lane >= d) inc += tt;
    }
    __shared__ int wsum[4];
    if (lane == 63) wsum[wid] = inc;
    __syncthreads();
    int woff = 0;
#pragma unroll
    for (int w = 0; w < 4; ++w)
        if (w < wid) woff += wsum[w];
    boff[t] = woff + inc - v;
}

__global__ __launch_bounds__(256) void k_scan3(int* __restrict__ rp, const int* __restrict__ boff) {
    int i = blockIdx.x * 256 + threadIdx.x;
    if (i < NN) rp[i] += boff[i >> 8];
    else if (i == NN) rp[NN] = NE;
}

// edge record: {src*128 byte-offset into fp8 row buffers, ewt bits} -> one 8B store
__global__ __launch_bounds__(256) void k_scatter(const int* __restrict__ src, const int* __restrict__ dst,
                                                 const float* __restrict__ dinv, const int* __restrict__ rp,
                                                 int* __restrict__ cnt, uint2* __restrict__ edges) {
    int e = blockIdx.x * 256 + threadIdx.x;
    if (e >= NE) return;
    int s = src[e], d = dst[e];
    int pos = rp[d] + atomicAdd(&cnt[d], 1);
    uint2 rec;
    rec.x = (unsigned)s * 128u;           // byte offset of row s (64 ch * 2B)
    rec.y = __float_as_uint(dinv[s] * dinv[d]);
    edges[pos] = rec;
}

// ---------------- lift: h = [tanh(x @ lift_w^T + b), ones]; writes layer-0 z0 ----

#define LIFT_NPB 16

__global__ __launch_bounds__(256) void k_lift(const float* __restrict__ x, const float* __restrict__ lw,
                                              const float* __restrict__ lb,
                                              const float* __restrict__ alpha, const float* __restrict__ beta,
                                              const float* __restrict__ dxp, const float* __restrict__ dyp,
                                              float* __restrict__ h, unsigned short* __restrict__ z0bf8) {
    __shared__ unsigned Wt2[CIN / 2][HH + 1];
    __shared__ float xs[LIFT_NPB][CIN];
    int t = threadIdx.x;
    for (int idx = t; idx < (CIN / 2) * HH; idx += 256) {
        int c = idx & 63, kk = idx >> 6;
        Wt2[kk][c] = pack_bf2(lw[c * CIN + 2 * kk], lw[c * CIN + 2 * kk + 1]);
    }
    int n0 = blockIdx.x * LIFT_NPB;
#pragma unroll
    for (int i = 0; i < LIFT_NPB * CIN / 256; ++i) {
        int idx = i * 256 + t;
        int r = idx >> 7, c = idx & 127;
        xs[r][c] = x[(size_t)(n0 + r) * CIN + c];
    }
    __syncthreads();
    int lane = t & 63, wid = t >> 6;
    float bias = lb[lane];
    float a = alpha[0], b = beta[0];
    float idx0 = 1.0f / (1.0f + DTC * dxp[0]);
    float idy0 = 1.0f / (1.0f + DTC * dyp[0]);
#pragma unroll
    for (int i = 0; i < 4; ++i) {
        int nl = wid * 4 + i;
        float acc0 = 0.f, acc1 = 0.f;
        const float2* xr = (const float2*)&xs[nl][0];
#pragma unroll 8
        for (int kk = 0; kk < CIN / 2; ++kk) {
            float2 xv = xr[kk];
            float2 wv = unpack_bf2(Wt2[kk][lane]);
            acc0 = fmaf(xv.x, wv.x, acc0);
            acc1 = fmaf(xv.y, wv.y, acc1);
        }
        float hx = tanhf(bias + acc0 + acc1);
        int n = n0 + nl;
        float* hr = h + (size_t)n * 128;
        hr[lane] = hx;
        hr[HH + lane] = 1.0f;
        // layer-0 z0 = rhs/diag with (X,Y)=(hx,1): xy = hx
        float rx = hx + DTC * (a * hx - b * hx);
        float ry = 1.0f + DTC * (b * hx - a);
        z0bf8[(size_t)n * HH + lane] = pack_fp8x2(rx * idx0, ry * idy0);
    }
}

// ---------------- gather core: explicit 2-stage ping-pong pipeline ----------------

#define LOADB(ED, G)                                                              \
    do {                                                                          \
        _Pragma("unroll") for (int u = 0; u < 8; ++u) ED[u] = edges[e + u];       \
        _Pragma("unroll") for (int u = 0; u < 8; ++u)                             \
            G[u] = *(const unsigned short*)(base + ED[u].x + lane2);              \
        e += 8;                                                                   \
    } while (0)

#define CONSB(ED, G)                                                              \
    do {                                                                          \
        _Pragma("unroll") for (int u = 0; u < 8; ++u) {                           \
            float w = __uint_as_float(ED[u].y);                                   \
            float2 v = unpack_fp8x2(G[u]);                                        \
            accX = fmaf(w, v.x, accX);                                            \
            accY = fmaf(w, v.y, accY);                                            \
        }                                                                         \
    } while (0)

__device__ __forceinline__ void gather_acc(const unsigned short* __restrict__ srcbuf,
                                           const uint2* __restrict__ edges,
                                           int e0, int e1, int lane2, float& accX, float& accY) {
    const char* base = (const char*)srcbuf;
    int e = e0;
    int nfull = (e1 - e0) >> 3;
    uint2 edA[8], edB[8];
    unsigned short gA[8], gB[8];
    if (nfull > 0) {
        LOADB(edA, gA);
        int ib = 1;
        for (; ib + 1 < nfull; ib += 2) {
            LOADB(edB, gB);     // issue batch i+1 while batch i results in flight
            CONSB(edA, gA);
            LOADB(edA, gA);
            CONSB(edB, gB);
        }
        if (ib < nfull) {
            LOADB(edB, gB);
            CONSB(edA, gA);
            CONSB(edB, gB);
        } else {
            CONSB(edA, gA);
        }
    }
    for (; e < e1; ++e) {
        uint2 ed = edges[e];
        float w = __uint_as_float(ed.y);
        float2 v = unpack_fp8x2(*(const unsigned short*)(base + ed.x + lane2));
        accX = fmaf(w, v.x, accX);
        accY = fmaf(w, v.y, accY);
    }
}

// ---------------- phase kernels ----------------
// phase1: z1 = z0_own(fp8) + c*(S.z0) — no fp32 h access at all.

__global__ __launch_bounds__(256, 4) void k_phase1(const unsigned short* __restrict__ z0bf8,
                                                   unsigned short* __restrict__ z1bf8,
                                                   const int* __restrict__ rp, const uint2* __restrict__ edges,
                                                   const float* __restrict__ dxp, const float* __restrict__ dyp,
                                                   int l) {
    int lane = threadIdx.x & 63, wid = threadIdx.x >> 6;
    int n = blockIdx.x * 4 + wid;
    float dx = dxp[l], dy = dyp[l];
    float cx = DTC * dx / (1.0f + DTC * dx);
    float cy = DTC * dy / (1.0f + DTC * dy);
    float accX = 0.f, accY = 0.f;
    gather_acc(z0bf8, edges, rp[n], rp[n + 1], lane * 2, accX, accY);
    float2 z0 = unpack_fp8x2(z0bf8[(size_t)n * HH + lane]);
    z1bf8[(size_t)n * HH + lane] = pack_fp8x2(fmaf(cx, accX, z0.x), fmaf(cy, accY, z0.y));
}

// phase2: z2 = z0_own(fp32, recomputed) + c*(S.z1); gate + LN; h in place; next-layer z0.

__global__ __launch_bounds__(256, 4) void k_phase2(float* __restrict__ h,
                                                   unsigned short* __restrict__ z0bf8,
                                                   const unsigned short* __restrict__ z1bf8,
                                                   const int* __restrict__ rp, const uint2* __restrict__ edges,
                                                   const float* __restrict__ alpha, const float* __restrict__ beta,
                                                   const float* __restrict__ dxp, const float* __restrict__ dyp,
                                                   const float* __restrict__ taup,
                                                   const float* __restrict__ lnw, const float* __restrict__ lnb,
                                                   int l) {
    int lane = threadIdx.x & 63, wid = threadIdx.x >> 6;
    int n = blockIdx.x * 4 + wid;
    float a = alpha[l], b = beta[l], dx = dxp[l], dy = dyp[l];
    float idx_ = 1.0f / (1.0f + DTC * dx);
    float idy_ = 1.0f / (1.0f + DTC * dy);
    float cx = DTC * dx * idx_, cy = DTC * dy * idy_;
    float accX = 0.f, accY = 0.f;
    gather_acc(z1bf8, edges, rp[n], rp[n + 1], lane * 2, accX, accY);
    float* hn = h + (size_t)n * 128;
    float hx = hn[lane], hy = hn[HH + lane];
    float xy = hx * hy;
    float z0x = (hx + DTC * (a * hx - b * xy)) * idx_;
    float z0y = (hy + DTC * (b * xy - a * hy)) * idy_;
    float z2x = fmaf(cx, accX, z0x);
    float z2y = fmaf(cy, accY, z0y);
    float g = 1.0f / (1.0f + expf(-taup[l]));
    float nx = fmaf(g, z2x - hx, hx);
    float ny = fmaf(g, z2y - hy, hy);
    float s1 = nx + ny;
    float s2 = fmaf(nx, nx, ny * ny);
#pragma unroll
    for (int m = 1; m < 64; m <<= 1) {
        s1 += __shfl_xor(s1, m, 64);
        s2 += __shfl_xor(s2, m, 64);
    }
    float mean = s1 * (1.0f / 128.0f);
    float var = fmaf(-mean, mean, s2 * (1.0f / 128.0f));
    float rstd = rsqrtf(var + LNEPS);
    float ox = fmaf((nx - mean) * rstd, lnw[(size_t)l * 128 + lane], lnb[(size_t)l * 128 + lane]);
    float oy = fmaf((ny - mean) * rstd, lnw[(size_t)l * 128 + HH + lane], lnb[(size_t)l * 128 + HH + lane]);
    hn[lane] = ox;
    hn[HH + lane] = oy;
    if (l + 1 < NL) {
        float a2 = alpha[l + 1], b2 = beta[l + 1];
        float idx2 = 1.0f / (1.0f + DTC * dxp[l + 1]);
        float idy2 = 1.0f / (1.0f + DTC * dyp[l + 1]);
        float xy2 = ox * oy;
        float r2x = ox + DTC * (a2 * ox - b2 * xy2);
        float r2y = oy + DTC * (b2 * xy2 - a2 * oy);
        z0bf8[(size_t)n * HH + lane] = pack_fp8x2(r2x * idx2, r2y * idy2);
    }
}

// ---------------- output head ----------------

__global__ __launch_bounds__(256) void k_out(const float* __restrict__ h, const float* __restrict__ ow,
                                             const float* __restrict__ ob, const float* __restrict__ lsp,
                                             float* __restrict__ out) {
    __shared__ float hs[64][65];
    __shared__ float ows[NCLS][65];
    __shared__ float obs[NCLS];
    int t = threadIdx.x;
    int n0 = blockIdx.x * 64;
#pragma unroll
    for (int i = 0; i < 16; ++i) {
        int idx = i * 256 + t;
        int r = idx >> 6, c = idx & 63;
        int n = n0 + r;
        hs[r][c] = (n < NN) ? h[(size_t)n * 128 + c] : 0.f;
    }
#pragma unroll
    for (int i = 0; i < 10; ++i) {
        int idx = i * 256 + t;
        int j = idx >> 6, c = idx & 63;
        ows[j][c] = ow[j * HH + c];
    }
    if (t < NCLS) obs[t] = ob[t];
    __syncthreads();
    float ls = lsp[0];
#pragma unroll
    for (int i = 0; i < 10; ++i) {
        int o = i * 256 + t;
        int nl = o / NCLS;
        int j = o - nl * NCLS;
        float acc = 0.f;
#pragma unroll 8
        for (int k = 0; k < HH; ++k) acc = fmaf(hs[nl][k], ows[j][k], acc);
        int n = n0 + nl;
        if (n < NN) out[(size_t)n * NCLS + j] = fmaf(ls, acc, obs[j]);
    }
}

// ---------------- launcher ----------------

extern "C" void kernel_launch(void* const* d_in, const int* in_sizes, int n_in,
                              void* d_out, int out_size, void* d_ws, size_t ws_size,
                              hipStream_t stream) {
    const float* x     = (const float*)d_in[0];
    const int*   ei    = (const int*)d_in[1];
    const float* lw    = (const float*)d_in[2];
    const float* lb    = (const float*)d_in[3];
    const float* alpha = (const float*)d_in[4];
    const float* beta  = (const float*)d_in[5];
    const float* dxp   = (const float*)d_in[6];
    const float* dyp   = (const float*)d_in[7];
    const float* taup  = (const float*)d_in[8];
    const float* lnw   = (const float*)d_in[9];
    const float* lnb   = (const float*)d_in[10];
    const float* ow    = (const float*)d_in[11];
    const float* ob    = (const float*)d_in[12];
    const float* lsp   = (const float*)d_in[13];
    float* out = (float*)d_out;

    const int* srcp = ei;
    const int* dstp = ei + NE;

    char* ws = (char*)d_ws;
    size_t o = 0;
    auto alloc = [&](size_t b) { size_t r = o; o += (b + 255) & ~(size_t)255; return r; };
    int*            row_ptr = (int*)(ws + alloc((NN + 1) * sizeof(int)));
    int*            deg     = (int*)(ws + alloc(NN * sizeof(int)));
    int*            cnt     = (int*)(ws + alloc(NN * sizeof(int)));
    float*          dinv    = (float*)(ws + alloc(NN * sizeof(float)));
    int*            bsum    = (int*)(ws + alloc(256 * sizeof(int)));
    int*            boff    = (int*)(ws + alloc(256 * sizeof(int)));
    uint2*          edges   = (uint2*)(ws + alloc((size_t)NE * sizeof(uint2)));
    float*          hbuf    = (float*)(ws + alloc((size_t)NN * 128 * sizeof(float)));
    unsigned short* z0bf8   = (unsigned short*)(ws + alloc((size_t)NN * HH * sizeof(unsigned short)));
    unsigned short* z1bf8   = (unsigned short*)(ws + alloc((size_t)NN * HH * sizeof(unsigned short)));

    hipMemsetAsync(deg, 0, NN * sizeof(int), stream);
    hipMemsetAsync(cnt, 0, NN * sizeof(int), stream);

    k_deg<<<(NE + 255) / 256, 256, 0, stream>>>(dstp, deg);
    k_scan1<<<NB_SCAN, 256, 0, stream>>>(deg, row_ptr, bsum, dinv);
    k_scan2<<<1, 256, 0, stream>>>(bsum, boff);
    k_scan3<<<NB_SCAN, 256, 0, stream>>>(row_ptr, boff);
    k_scatter<<<(NE + 255) / 256, 256, 0, stream>>>(srcp, dstp, dinv, row_ptr, cnt, edges);

    k_lift<<<NN / LIFT_NPB, 256, 0, stream>>>(x, lw, lb, alpha, beta, dxp, dyp, hbuf, z0bf8);

    for (int l = 0; l < NL; ++l) {
        k_phase1<<<NN / 4, 256, 0, stream>>>(z0bf8, z1bf8, row_ptr, edges, dxp, dyp, l);
        k_phase2<<<NN / 4, 256, 0, stream>>>(hbuf, z0bf8, z1bf8, row_ptr, edges,
                                             alpha, beta, dxp, dyp, taup, lnw, lnb, l);
    }

    k_out<<<(NN + 63) / 64, 256, 0, stream>>>(hbuf, ow, ob, lsp, out);
}

// Round 8
// 1077.995 us; speedup vs baseline: 1.3163x; 1.3163x over previous
//
#include <hip/hip_runtime.h>

#define NN 50000
#define NE 800000
#define CIN 128
#define HH 64
#define NCLS 40
#define NL 15
#define DTC 0.1f
#define LNEPS 1e-5f
#define NB_SCAN 196   // ceil(50000/256)

typedef float f32x2 __attribute__((ext_vector_type(2)));

// ---------------- bf16x2 / fp8x2 pack-unpack ----------------

__device__ inline unsigned pack_bf2(float x, float y) {
    unsigned ux = __float_as_uint(x);
    unsigned uy = __float_as_uint(y);
    ux = (ux + 0x7fffu + ((ux >> 16) & 1u)) >> 16;   // RNE
    uy = (uy + 0x7fffu + ((uy >> 16) & 1u)) >> 16;
    return ux | (uy << 16);
}
__device__ inline float2 unpack_bf2(unsigned p) {
    float2 r;
    r.x = __uint_as_float(p << 16);
    r.y = __uint_as_float(p & 0xffff0000u);
    return r;
}
__device__ inline unsigned short pack_fp8x2(float x, float y) {
    int r = __builtin_amdgcn_cvt_pk_fp8_f32(x, y, 0, false);
    return (unsigned short)(r & 0xffff);
}
__device__ inline float2 unpack_fp8x2(unsigned short p) {
    f32x2 v = __builtin_amdgcn_cvt_pk_f32_fp8((int)(unsigned)p, false);
    float2 r; r.x = v.x; r.y = v.y; return r;
}

// ---------------- degree / normalization precompute ----------------

__global__ __launch_bounds__(256) void k_deg(const int* __restrict__ dst, int* __restrict__ deg) {
    int e = blockIdx.x * 256 + threadIdx.x;
    if (e < NE) atomicAdd(&deg[dst[e]], 1);
}

__global__ __launch_bounds__(256) void k_scan1(const int* __restrict__ deg, int* __restrict__ rp,
                                               int* __restrict__ bsum, float* __restrict__ dinv) {
    int i = blockIdx.x * 256 + threadIdx.x;
    int v = (i < NN) ? deg[i] : 0;
    if (i < NN) dinv[i] = rsqrtf(fmaxf((float)v, 1.0f));
    int lane = threadIdx.x & 63, wid = threadIdx.x >> 6;
    int inc = v;
#pragma unroll
    for (int d = 1; d < 64; d <<= 1) {
        int t = __shfl_up(inc, d, 64);
        if (lane >= d) inc += t;
    }
    __shared__ int wsum[4];
    if (lane == 63) wsum[wid] = inc;
    __syncthreads();
    int woff = 0;
#pragma unroll
    for (int w = 0; w < 4; ++w)
        if (w < wid) woff += wsum[w];
    if (i < NN) rp[i] = woff + inc - v;
    if (threadIdx.x == 255) bsum[blockIdx.x] = woff + inc;
}

__global__ __launch_bounds__(256) void k_scan2(const int* __restrict__ bsum, int* __restrict__ boff) {
    int t = threadIdx.x;
    int v = (t < NB_SCAN) ? bsum[t] : 0;
    int lane = t & 63, wid = t >> 6;
    int inc = v;
#pragma unroll
    for (int d = 1; d < 64; d <<= 1) {
        int tt = __shfl_up(inc, d, 64);
        if (lane >= d) inc += tt;
    }
    __shared__ int wsum[4];
    if (lane == 63) wsum[wid] = inc;
    __syncthreads();
    int woff = 0;
#pragma unroll
    for (int w = 0; w < 4; ++w)
        if (w < wid) woff += wsum[w];
    boff[t] = woff + inc - v;
}

__global__ __launch_bounds__(256) void k_scan3(int* __restrict__ rp, const int* __restrict__ boff) {
    int i = blockIdx.x * 256 + threadIdx.x;
    if (i < NN) rp[i] += boff[i >> 8];
    else if (i == NN) rp[NN] = NE;
}

// edge record: {src*128 byte-offset into fp8 row buffers, ewt bits} -> one 8B store
__global__ __launch_bounds__(256) void k_scatter(const int* __restrict__ src, const int* __restrict__ dst,
                                                 const float* __restrict__ dinv, const int* __restrict__ rp,
                                                 int* __restrict__ cnt, uint2* __restrict__ edges) {
    int e = blockIdx.x * 256 + threadIdx.x;
    if (e >= NE) return;
    int s = src[e], d = dst[e];
    int pos = rp[d] + atomicAdd(&cnt[d], 1);
    uint2 rec;
    rec.x = (unsigned)s * 128u;           // byte offset of row s (64 ch * 2B)
    rec.y = __float_as_uint(dinv[s] * dinv[d]);
    edges[pos] = rec;
}

// ---------------- lift: h = [tanh(x @ lift_w^T + b), ones]; writes layer-0 z0 ----

#define LIFT_NPB 16

__global__ __launch_bounds__(256) void k_lift(const float* __restrict__ x, const float* __restrict__ lw,
                                              const float* __restrict__ lb,
                                              const float* __restrict__ alpha, const float* __restrict__ beta,
                                              const float* __restrict__ dxp, const float* __restrict__ dyp,
                                              float* __restrict__ h, unsigned short* __restrict__ z0bf8) {
    __shared__ unsigned Wt2[CIN / 2][HH + 1];
    __shared__ float xs[LIFT_NPB][CIN];
    int t = threadIdx.x;
    for (int idx = t; idx < (CIN / 2) * HH; idx += 256) {
        int c = idx & 63, kk = idx >> 6;
        Wt2[kk][c] = pack_bf2(lw[c * CIN + 2 * kk], lw[c * CIN + 2 * kk + 1]);
    }
    int n0 = blockIdx.x * LIFT_NPB;
#pragma unroll
    for (int i = 0; i < LIFT_NPB * CIN / 256; ++i) {
        int idx = i * 256 + t;
        int r = idx >> 7, c = idx & 127;
        xs[r][c] = x[(size_t)(n0 + r) * CIN + c];
    }
    __syncthreads();
    int lane = t & 63, wid = t >> 6;
    float bias = lb[lane];
    float a = alpha[0], b = beta[0];
    float idx0 = 1.0f / (1.0f + DTC * dxp[0]);
    float idy0 = 1.0f / (1.0f + DTC * dyp[0]);
#pragma unroll
    for (int i = 0; i < 4; ++i) {
        int nl = wid * 4 + i;
        float acc0 = 0.f, acc1 = 0.f;
        const float2* xr = (const float2*)&xs[nl][0];
#pragma unroll 8
        for (int kk = 0; kk < CIN / 2; ++kk) {
            float2 xv = xr[kk];
            float2 wv = unpack_bf2(Wt2[kk][lane]);
            acc0 = fmaf(xv.x, wv.x, acc0);
            acc1 = fmaf(xv.y, wv.y, acc1);
        }
        float hx = tanhf(bias + acc0 + acc1);
        int n = n0 + nl;
        float* hr = h + (size_t)n * 128;
        hr[lane] = hx;
        hr[HH + lane] = 1.0f;
        // layer-0 z0 = rhs/diag with (X,Y)=(hx,1): xy = hx
        float rx = hx + DTC * (a * hx - b * hx);
        float ry = 1.0f + DTC * (b * hx - a);
        z0bf8[(size_t)n * HH + lane] = pack_fp8x2(rx * idx0, ry * idy0);
    }
}

// ---------------- gather core ----------------
// e0/e1 MUST be wave-uniform SGPR values (readfirstlane'd by caller) so the
// uint4 edge-record loads are uniform -> scalar (SMEM) loads, off the VMEM path.

__device__ __forceinline__ void gather_acc(const unsigned short* __restrict__ srcbuf,
                                           const uint2* __restrict__ edges,
                                           int e0, int e1, int lane2, float& accX, float& accY) {
    const char* base = (const char*)srcbuf;
    int e = e0;
    if ((e & 1) && e < e1) {           // align to 16B record pairs
        uint2 ed = edges[e];
        float w = __uint_as_float(ed.y);
        float2 v = unpack_fp8x2(*(const unsigned short*)(base + ed.x + lane2));
        accX = fmaf(w, v.x, accX);
        accY = fmaf(w, v.y, accY);
        ++e;
    }
    for (; e + 8 <= e1; e += 8) {
        uint4 q0 = *(const uint4*)(edges + e);       // uniform: 2 records
        uint4 q1 = *(const uint4*)(edges + e + 2);
        uint4 q2 = *(const uint4*)(edges + e + 4);
        uint4 q3 = *(const uint4*)(edges + e + 6);
        unsigned short g0 = *(const unsigned short*)(base + q0.x + lane2);
        unsigned short g1 = *(const unsigned short*)(base + q0.z + lane2);
        unsigned short g2 = *(const unsigned short*)(base + q1.x + lane2);
        unsigned short g3 = *(const unsigned short*)(base + q1.z + lane2);
        unsigned short g4 = *(const unsigned short*)(base + q2.x + lane2);
        unsigned short g5 = *(const unsigned short*)(base + q2.z + lane2);
        unsigned short g6 = *(const unsigned short*)(base + q3.x + lane2);
        unsigned short g7 = *(const unsigned short*)(base + q3.z + lane2);
        float2 v;
        v = unpack_fp8x2(g0); accX = fmaf(__uint_as_float(q0.y), v.x, accX); accY = fmaf(__uint_as_float(q0.y), v.y, accY);
        v = unpack_fp8x2(g1); accX = fmaf(__uint_as_float(q0.w), v.x, accX); accY = fmaf(__uint_as_float(q0.w), v.y, accY);
        v = unpack_fp8x2(g2); accX = fmaf(__uint_as_float(q1.y), v.x, accX); accY = fmaf(__uint_as_float(q1.y), v.y, accY);
        v = unpack_fp8x2(g3); accX = fmaf(__uint_as_float(q1.w), v.x, accX); accY = fmaf(__uint_as_float(q1.w), v.y, accY);
        v = unpack_fp8x2(g4); accX = fmaf(__uint_as_float(q2.y), v.x, accX); accY = fmaf(__uint_as_float(q2.y), v.y, accY);
        v = unpack_fp8x2(g5); accX = fmaf(__uint_as_float(q2.w), v.x, accX); accY = fmaf(__uint_as_float(q2.w), v.y, accY);
        v = unpack_fp8x2(g6); accX = fmaf(__uint_as_float(q3.y), v.x, accX); accY = fmaf(__uint_as_float(q3.y), v.y, accY);
        v = unpack_fp8x2(g7); accX = fmaf(__uint_as_float(q3.w), v.x, accX); accY = fmaf(__uint_as_float(q3.w), v.y, accY);
    }
    for (; e < e1; ++e) {
        uint2 ed = edges[e];
        float w = __uint_as_float(ed.y);
        float2 v = unpack_fp8x2(*(const unsigned short*)(base + ed.x + lane2));
        accX = fmaf(w, v.x, accX);
        accY = fmaf(w, v.y, accY);
    }
}

// ---------------- phase kernels ----------------
// phase1: z1 = z0_own(fp8) + c*(S.z0) — no fp32 h access at all.

__global__ __launch_bounds__(256) void k_phase1(const unsigned short* __restrict__ z0bf8,
                                                unsigned short* __restrict__ z1bf8,
                                                const int* __restrict__ rp, const uint2* __restrict__ edges,
                                                const float* __restrict__ dxp, const float* __restrict__ dyp,
                                                int l) {
    int lane = threadIdx.x & 63, wid = threadIdx.x >> 6;
    int n = blockIdx.x * 4 + wid;
    float dx = dxp[l], dy = dyp[l];
    float cx = DTC * dx / (1.0f + DTC * dx);
    float cy = DTC * dy / (1.0f + DTC * dy);
    int e0 = __builtin_amdgcn_readfirstlane(rp[n]);
    int e1 = __builtin_amdgcn_readfirstlane(rp[n + 1]);
    float accX = 0.f, accY = 0.f;
    gather_acc(z0bf8, edges, e0, e1, lane * 2, accX, accY);
    float2 z0 = unpack_fp8x2(z0bf8[(size_t)n * HH + lane]);
    z1bf8[(size_t)n * HH + lane] = pack_fp8x2(fmaf(cx, accX, z0.x), fmaf(cy, accY, z0.y));
}

// phase2: z2 = z0_own(fp32, recomputed) + c*(S.z1); gate + LN; h in place; next-layer z0.

__global__ __launch_bounds__(256) void k_phase2(float* __restrict__ h,
                                                unsigned short* __restrict__ z0bf8,
                                                const unsigned short* __restrict__ z1bf8,
                                                const int* __restrict__ rp, const uint2* __restrict__ edges,
                                                const float* __restrict__ alpha, const float* __restrict__ beta,
                                                const float* __restrict__ dxp, const float* __restrict__ dyp,
                                                const float* __restrict__ taup,
                                                const float* __restrict__ lnw, const float* __restrict__ lnb,
                                                int l) {
    int lane = threadIdx.x & 63, wid = threadIdx.x >> 6;
    int n = blockIdx.x * 4 + wid;
    float a = alpha[l], b = beta[l], dx = dxp[l], dy = dyp[l];
    float idx_ = 1.0f / (1.0f + DTC * dx);
    float idy_ = 1.0f / (1.0f + DTC * dy);
    float cx = DTC * dx * idx_, cy = DTC * dy * idy_;
    int e0 = __builtin_amdgcn_readfirstlane(rp[n]);
    int e1 = __builtin_amdgcn_readfirstlane(rp[n + 1]);
    float accX = 0.f, accY = 0.f;
    gather_acc(z1bf8, edges, e0, e1, lane * 2, accX, accY);
    float* hn = h + (size_t)n * 128;
    float hx = hn[lane], hy = hn[HH + lane];
    float xy = hx * hy;
    float z0x = (hx + DTC * (a * hx - b * xy)) * idx_;
    float z0y = (hy + DTC * (b * xy - a * hy)) * idy_;
    float z2x = fmaf(cx, accX, z0x);
    float z2y = fmaf(cy, accY, z0y);
    float g = 1.0f / (1.0f + expf(-taup[l]));
    float nx = fmaf(g, z2x - hx, hx);
    float ny = fmaf(g, z2y - hy, hy);
    float s1 = nx + ny;
    float s2 = fmaf(nx, nx, ny * ny);
#pragma unroll
    for (int m = 1; m < 64; m <<= 1) {
        s1 += __shfl_xor(s1, m, 64);
        s2 += __shfl_xor(s2, m, 64);
    }
    float mean = s1 * (1.0f / 128.0f);
    float var = fmaf(-mean, mean, s2 * (1.0f / 128.0f));
    float rstd = rsqrtf(var + LNEPS);
    float ox = fmaf((nx - mean) * rstd, lnw[(size_t)l * 128 + lane], lnb[(size_t)l * 128 + lane]);
    float oy = fmaf((ny - mean) * rstd, lnw[(size_t)l * 128 + HH + lane], lnb[(size_t)l * 128 + HH + lane]);
    hn[lane] = ox;
    hn[HH + lane] = oy;
    if (l + 1 < NL) {
        float a2 = alpha[l + 1], b2 = beta[l + 1];
        float idx2 = 1.0f / (1.0f + DTC * dxp[l + 1]);
        float idy2 = 1.0f / (1.0f + DTC * dyp[l + 1]);
        float xy2 = ox * oy;
        float r2x = ox + DTC * (a2 * ox - b2 * xy2);
        float r2y = oy + DTC * (b2 * xy2 - a2 * oy);
        z0bf8[(size_t)n * HH + lane] = pack_fp8x2(r2x * idx2, r2y * idy2);
    }
}

// ---------------- output head ----------------

__global__ __launch_bounds__(256) void k_out(const float* __restrict__ h, const float* __restrict__ ow,
                                             const float* __restrict__ ob, const float* __restrict__ lsp,
                                             float* __restrict__ out) {
    __shared__ float hs[64][65];
    __shared__ float ows[NCLS][65];
    __shared__ float obs[NCLS];
    int t = threadIdx.x;
    int n0 = blockIdx.x * 64;
#pragma unroll
    for (int i = 0; i < 16; ++i) {
        int idx = i * 256 + t;
        int r = idx >> 6, c = idx & 63;
        int n = n0 + r;
        hs[r][c] = (n < NN) ? h[(size_t)n * 128 + c] : 0.f;
    }
#pragma unroll
    for (int i = 0; i < 10; ++i) {
        int idx = i * 256 + t;
        int j = idx >> 6, c = idx & 63;
        ows[j][c] = ow[j * HH + c];
    }
    if (t < NCLS) obs[t] = ob[t];
    __syncthreads();
    float ls = lsp[0];
#pragma unroll
    for (int i = 0; i < 10; ++i) {
        int o = i * 256 + t;
        int nl = o / NCLS;
        int j = o - nl * NCLS;
        float acc = 0.f;
#pragma unroll 8
        for (int k = 0; k < HH; ++k) acc = fmaf(hs[nl][k], ows[j][k], acc);
        int n = n0 + nl;
        if (n < NN) out[(size_t)n * NCLS + j] = fmaf(ls, acc, obs[j]);
    }
}

// ---------------- launcher ----------------

extern "C" void kernel_launch(void* const* d_in, const int* in_sizes, int n_in,
                              void* d_out, int out_size, void* d_ws, size_t ws_size,
                              hipStream_t stream) {
    const float* x     = (const float*)d_in[0];
    const int*   ei    = (const int*)d_in[1];
    const float* lw    = (const float*)d_in[2];
    const float* lb    = (const float*)d_in[3];
    const float* alpha = (const float*)d_in[4];
    const float* beta  = (const float*)d_in[5];
    const float* dxp   = (const float*)d_in[6];
    const float* dyp   = (const float*)d_in[7];
    const float* taup  = (const float*)d_in[8];
    const float* lnw   = (const float*)d_in[9];
    const float* lnb   = (const float*)d_in[10];
    const float* ow    = (const float*)d_in[11];
    const float* ob    = (const float*)d_in[12];
    const float* lsp   = (const float*)d_in[13];
    float* out = (float*)d_out;

    const int* srcp = ei;
    const int* dstp = ei + NE;

    char* ws = (char*)d_ws;
    size_t o = 0;
    auto alloc = [&](size_t b) { size_t r = o; o += (b + 255) & ~(size_t)255; return r; };
    int*            row_ptr = (int*)(ws + alloc((NN + 1) * sizeof(int)));
    int*            deg     = (int*)(ws + alloc(NN * sizeof(int)));
    int*            cnt     = (int*)(ws + alloc(NN * sizeof(int)));
    float*          dinv    = (float*)(ws + alloc(NN * sizeof(float)));
    int*            bsum    = (int*)(ws + alloc(256 * sizeof(int)));
    int*            boff    = (int*)(ws + alloc(256 * sizeof(int)));
    uint2*          edges   = (uint2*)(ws + alloc((size_t)NE * sizeof(uint2)));
    float*          hbuf    = (float*)(ws + alloc((size_t)NN * 128 * sizeof(float)));
    unsigned short* z0bf8   = (unsigned short*)(ws + alloc((size_t)NN * HH * sizeof(unsigned short)));
    unsigned short* z1bf8   = (unsigned short*)(ws + alloc((size_t)NN * HH * sizeof(unsigned short)));

    hipMemsetAsync(deg, 0, NN * sizeof(int), stream);
    hipMemsetAsync(cnt, 0, NN * sizeof(int), stream);

    k_deg<<<(NE + 255) / 256, 256, 0, stream>>>(dstp, deg);
    k_scan1<<<NB_SCAN, 256, 0, stream>>>(deg, row_ptr, bsum, dinv);
    k_scan2<<<1, 256, 0, stream>>>(bsum, boff);
    k_scan3<<<NB_SCAN, 256, 0, stream>>>(row_ptr, boff);
    k_scatter<<<(NE + 255) / 256, 256, 0, stream>>>(srcp, dstp, dinv, row_ptr, cnt, edges);

    k_lift<<<NN / LIFT_NPB, 256, 0, stream>>>(x, lw, lb, alpha, beta, dxp, dyp, hbuf, z0bf8);

    for (int l = 0; l < NL; ++l) {
        k_phase1<<<NN / 4, 256, 0, stream>>>(z0bf8, z1bf8, row_ptr, edges, dxp, dyp, l);
        k_phase2<<<NN / 4, 256, 0, stream>>>(hbuf, z0bf8, z1bf8, row_ptr, edges,
                                             alpha, beta, dxp, dyp, taup, lnw, lnb, l);
    }

    k_out<<<(NN + 63) / 64, 256, 0, stream>>>(hbuf, ow, ob, lsp, out);
}

// Round 9
// 1003.176 us; speedup vs baseline: 1.4145x; 1.0746x over previous
//
#include <hip/hip_runtime.h>

#define NN 50000
#define NE 800000
#define CIN 128
#define HH 64
#define NCLS 40
#define NL 15
#define DTC 0.1f
#define LNEPS 1e-5f
#define NB_SCAN 196   // ceil(50000/256)

typedef float f32x2 __attribute__((ext_vector_type(2)));

// ---------------- bf16x2 / fp8x2 pack-unpack ----------------

__device__ inline unsigned pack_bf2(float x, float y) {
    unsigned ux = __float_as_uint(x);
    unsigned uy = __float_as_uint(y);
    ux = (ux + 0x7fffu + ((ux >> 16) & 1u)) >> 16;   // RNE
    uy = (uy + 0x7fffu + ((uy >> 16) & 1u)) >> 16;
    return ux | (uy << 16);
}
__device__ inline float2 unpack_bf2(unsigned p) {
    float2 r;
    r.x = __uint_as_float(p << 16);
    r.y = __uint_as_float(p & 0xffff0000u);
    return r;
}
__device__ inline unsigned short pack_fp8x2(float x, float y) {
    int r = __builtin_amdgcn_cvt_pk_fp8_f32(x, y, 0, false);
    return (unsigned short)(r & 0xffff);
}
__device__ inline float2 unpack_fp8x2(unsigned short p) {
    f32x2 v = __builtin_amdgcn_cvt_pk_f32_fp8((int)(unsigned)p, false);
    float2 r; r.x = v.x; r.y = v.y; return r;
}

// ---------------- degree / normalization precompute ----------------

__global__ __launch_bounds__(256) void k_deg(const int* __restrict__ dst, int* __restrict__ deg) {
    int e = blockIdx.x * 256 + threadIdx.x;
    if (e < NE) atomicAdd(&deg[dst[e]], 1);
}

__global__ __launch_bounds__(256) void k_scan1(const int* __restrict__ deg, int* __restrict__ rp,
                                               int* __restrict__ bsum, float* __restrict__ dinv) {
    int i = blockIdx.x * 256 + threadIdx.x;
    int v = (i < NN) ? deg[i] : 0;
    if (i < NN) dinv[i] = rsqrtf(fmaxf((float)v, 1.0f));
    int lane = threadIdx.x & 63, wid = threadIdx.x >> 6;
    int inc = v;
#pragma unroll
    for (int d = 1; d < 64; d <<= 1) {
        int t = __shfl_up(inc, d, 64);
        if (lane >= d) inc += t;
    }
    __shared__ int wsum[4];
    if (lane == 63) wsum[wid] = inc;
    __syncthreads();
    int woff = 0;
#pragma unroll
    for (int w = 0; w < 4; ++w)
        if (w < wid) woff += wsum[w];
    if (i < NN) rp[i] = woff + inc - v;
    if (threadIdx.x == 255) bsum[blockIdx.x] = woff + inc;
}

__global__ __launch_bounds__(256) void k_scan2(const int* __restrict__ bsum, int* __restrict__ boff) {
    int t = threadIdx.x;
    int v = (t < NB_SCAN) ? bsum[t] : 0;
    int lane = t & 63, wid = t >> 6;
    int inc = v;
#pragma unroll
    for (int d = 1; d < 64; d <<= 1) {
        int tt = __shfl_up(inc, d, 64);
        if (lane >= d) inc += tt;
    }
    __shared__ int wsum[4];
    if (lane == 63) wsum[wid] = inc;
    __syncthreads();
    int woff = 0;
#pragma unroll
    for (int w = 0; w < 4; ++w)
        if (w < wid) woff += wsum[w];
    boff[t] = woff + inc - v;
}

__global__ __launch_bounds__(256) void k_scan3(int* __restrict__ rp, const int* __restrict__ boff) {
    int i = blockIdx.x * 256 + threadIdx.x;
    if (i < NN) rp[i] += boff[i >> 8];
    else if (i == NN) rp[NN] = NE;
}

// edge record: {src*128 byte-offset into fp8 row buffers, ewt bits} -> one 8B store
__global__ __launch_bounds__(256) void k_scatter(const int* __restrict__ src, const int* __restrict__ dst,
                                                 const float* __restrict__ dinv, const int* __restrict__ rp,
                                                 int* __restrict__ cnt, uint2* __restrict__ edges) {
    int e = blockIdx.x * 256 + threadIdx.x;
    if (e >= NE) return;
    int s = src[e], d = dst[e];
    int pos = rp[d] + atomicAdd(&cnt[d], 1);
    uint2 rec;
    rec.x = (unsigned)s * 128u;           // byte offset of row s (64 ch * 2B)
    rec.y = __float_as_uint(dinv[s] * dinv[d]);
    edges[pos] = rec;
}

// ---------------- lift: h = [tanh(x @ lift_w^T + b), ones]; writes layer-0 z0 ----
// kk-outer / node-inner: W unpacked once per kk, 4 node accumulators.

#define LIFT_NPB 16

__global__ __launch_bounds__(256) void k_lift(const float* __restrict__ x, const float* __restrict__ lw,
                                              const float* __restrict__ lb,
                                              const float* __restrict__ alpha, const float* __restrict__ beta,
                                              const float* __restrict__ dxp, const float* __restrict__ dyp,
                                              float* __restrict__ h, unsigned short* __restrict__ z0bf8) {
    __shared__ unsigned Wt2[CIN / 2][HH + 1];
    __shared__ float xs[LIFT_NPB][CIN];
    int t = threadIdx.x;
    for (int idx = t; idx < (CIN / 2) * HH; idx += 256) {
        int c = idx & 63, kk = idx >> 6;
        Wt2[kk][c] = pack_bf2(lw[c * CIN + 2 * kk], lw[c * CIN + 2 * kk + 1]);
    }
    int n0 = blockIdx.x * LIFT_NPB;
#pragma unroll
    for (int i = 0; i < LIFT_NPB * CIN / 256; ++i) {
        int idx = i * 256 + t;
        int r = idx >> 7, c = idx & 127;
        xs[r][c] = x[(size_t)(n0 + r) * CIN + c];
    }
    __syncthreads();
    int lane = t & 63, wid = t >> 6;
    float bias = lb[lane];
    float a = alpha[0], b = beta[0];
    float idx0 = 1.0f / (1.0f + DTC * dxp[0]);
    float idy0 = 1.0f / (1.0f + DTC * dyp[0]);
    const float2* x0 = (const float2*)&xs[wid * 4 + 0][0];
    const float2* x1 = (const float2*)&xs[wid * 4 + 1][0];
    const float2* x2 = (const float2*)&xs[wid * 4 + 2][0];
    const float2* x3 = (const float2*)&xs[wid * 4 + 3][0];
    float ac0 = 0.f, ac1 = 0.f, ac2 = 0.f, ac3 = 0.f;
#pragma unroll 8
    for (int kk = 0; kk < CIN / 2; ++kk) {
        float2 wv = unpack_bf2(Wt2[kk][lane]);
        float2 v0 = x0[kk], v1 = x1[kk], v2 = x2[kk], v3 = x3[kk];
        ac0 = fmaf(v0.y, wv.y, fmaf(v0.x, wv.x, ac0));
        ac1 = fmaf(v1.y, wv.y, fmaf(v1.x, wv.x, ac1));
        ac2 = fmaf(v2.y, wv.y, fmaf(v2.x, wv.x, ac2));
        ac3 = fmaf(v3.y, wv.y, fmaf(v3.x, wv.x, ac3));
    }
#pragma unroll
    for (int i = 0; i < 4; ++i) {
        float acc = i == 0 ? ac0 : i == 1 ? ac1 : i == 2 ? ac2 : ac3;
        float hx = tanhf(bias + acc);
        int n = n0 + wid * 4 + i;
        float* hr = h + (size_t)n * 128;
        hr[lane] = hx;
        hr[HH + lane] = 1.0f;
        // layer-0 z0 = rhs/diag with (X,Y)=(hx,1): xy = hx
        float rx = hx + DTC * (a * hx - b * hx);
        float ry = 1.0f + DTC * (b * hx - a);
        z0bf8[(size_t)n * HH + lane] = pack_fp8x2(rx * idx0, ry * idy0);
    }
}

// ---------------- gather core ----------------
// e ranges are wave-uniform SGPR values (readfirstlane'd) so uint4 edge-record
// loads become scalar (SMEM) loads, off the VMEM path.

__device__ __forceinline__ void batch8(const char* __restrict__ base, const uint2* __restrict__ edges,
                                       int e, int lane2, float& accX, float& accY) {
    uint4 q0 = *(const uint4*)(edges + e);
    uint4 q1 = *(const uint4*)(edges + e + 2);
    uint4 q2 = *(const uint4*)(edges + e + 4);
    uint4 q3 = *(const uint4*)(edges + e + 6);
    unsigned short g0 = *(const unsigned short*)(base + q0.x + lane2);
    unsigned short g1 = *(const unsigned short*)(base + q0.z + lane2);
    unsigned short g2 = *(const unsigned short*)(base + q1.x + lane2);
    unsigned short g3 = *(const unsigned short*)(base + q1.z + lane2);
    unsigned short g4 = *(const unsigned short*)(base + q2.x + lane2);
    unsigned short g5 = *(const unsigned short*)(base + q2.z + lane2);
    unsigned short g6 = *(const unsigned short*)(base + q3.x + lane2);
    unsigned short g7 = *(const unsigned short*)(base + q3.z + lane2);
    float2 v;
    v = unpack_fp8x2(g0); accX = fmaf(__uint_as_float(q0.y), v.x, accX); accY = fmaf(__uint_as_float(q0.y), v.y, accY);
    v = unpack_fp8x2(g1); accX = fmaf(__uint_as_float(q0.w), v.x, accX); accY = fmaf(__uint_as_float(q0.w), v.y, accY);
    v = unpack_fp8x2(g2); accX = fmaf(__uint_as_float(q1.y), v.x, accX); accY = fmaf(__uint_as_float(q1.y), v.y, accY);
    v = unpack_fp8x2(g3); accX = fmaf(__uint_as_float(q1.w), v.x, accX); accY = fmaf(__uint_as_float(q1.w), v.y, accY);
    v = unpack_fp8x2(g4); accX = fmaf(__uint_as_float(q2.y), v.x, accX); accY = fmaf(__uint_as_float(q2.y), v.y, accY);
    v = unpack_fp8x2(g5); accX = fmaf(__uint_as_float(q2.w), v.x, accX); accY = fmaf(__uint_as_float(q2.w), v.y, accY);
    v = unpack_fp8x2(g6); accX = fmaf(__uint_as_float(q3.y), v.x, accX); accY = fmaf(__uint_as_float(q3.y), v.y, accY);
    v = unpack_fp8x2(g7); accX = fmaf(__uint_as_float(q3.w), v.x, accX); accY = fmaf(__uint_as_float(q3.w), v.y, accY);
}

__device__ __forceinline__ void edge_one(const char* __restrict__ base, const uint2* __restrict__ edges,
                                         int e, int lane2, float& accX, float& accY) {
    uint2 ed = edges[e];
    float w = __uint_as_float(ed.y);
    float2 v = unpack_fp8x2(*(const unsigned short*)(base + ed.x + lane2));
    accX = fmaf(w, v.x, accX);
    accY = fmaf(w, v.y, accY);
}

// two independent rolling gather streams (nodes A and B) -> 2x memory parallelism
__device__ __forceinline__ void gather2(const unsigned short* __restrict__ srcbuf,
                                        const uint2* __restrict__ edges,
                                        int e0A, int e1A, int e0B, int e1B, int lane2,
                                        float& aXA, float& aYA, float& aXB, float& aYB) {
    const char* base = (const char*)srcbuf;
    int eA = e0A, eB = e0B;
    if ((eA & 1) && eA < e1A) { edge_one(base, edges, eA, lane2, aXA, aYA); ++eA; }
    if ((eB & 1) && eB < e1B) { edge_one(base, edges, eB, lane2, aXB, aYB); ++eB; }
    while (eA + 8 <= e1A && eB + 8 <= e1B) {
        batch8(base, edges, eA, lane2, aXA, aYA); eA += 8;
        batch8(base, edges, eB, lane2, aXB, aYB); eB += 8;
    }
    while (eA + 8 <= e1A) { batch8(base, edges, eA, lane2, aXA, aYA); eA += 8; }
    while (eB + 8 <= e1B) { batch8(base, edges, eB, lane2, aXB, aYB); eB += 8; }
    for (; eA < e1A; ++eA) edge_one(base, edges, eA, lane2, aXA, aYA);
    for (; eB < e1B; ++eB) edge_one(base, edges, eB, lane2, aXB, aYB);
}

// ---------------- phase kernels (2 nodes per wave) ----------------
// phase1: z1 = z0_own(fp8) + c*(S.z0) — no fp32 h access at all.

__global__ __launch_bounds__(256) void k_phase1(const unsigned short* __restrict__ z0bf8,
                                                unsigned short* __restrict__ z1bf8,
                                                const int* __restrict__ rp, const uint2* __restrict__ edges,
                                                const float* __restrict__ dxp, const float* __restrict__ dyp,
                                                int l) {
    int lane = threadIdx.x & 63, wid = threadIdx.x >> 6;
    int nA = blockIdx.x * 8 + wid * 2;       // grid = NN/8 = 6250
    int nB = nA + 1;
    float dx = dxp[l], dy = dyp[l];
    float cx = DTC * dx / (1.0f + DTC * dx);
    float cy = DTC * dy / (1.0f + DTC * dy);
    int e0A = __builtin_amdgcn_readfirstlane(rp[nA]);
    int e1A = __builtin_amdgcn_readfirstlane(rp[nA + 1]);
    int e1B = __builtin_amdgcn_readfirstlane(rp[nA + 2]);
    float aXA = 0.f, aYA = 0.f, aXB = 0.f, aYB = 0.f;
    gather2(z0bf8, edges, e0A, e1A, e1A, e1B, lane * 2, aXA, aYA, aXB, aYB);
    float2 zA = unpack_fp8x2(z0bf8[(size_t)nA * HH + lane]);
    float2 zB = unpack_fp8x2(z0bf8[(size_t)nB * HH + lane]);
    z1bf8[(size_t)nA * HH + lane] = pack_fp8x2(fmaf(cx, aXA, zA.x), fmaf(cy, aYA, zA.y));
    z1bf8[(size_t)nB * HH + lane] = pack_fp8x2(fmaf(cx, aXB, zB.x), fmaf(cy, aYB, zB.y));
}

// phase2: z2 = z0_own(fp32, recomputed) + c*(S.z1); gate + LN; h in place; next-layer z0.

__device__ __forceinline__ void phase2_epi(int n, int lane, float accX, float accY,
                                           float* __restrict__ h, unsigned short* __restrict__ z0bf8,
                                           float a, float b, float idx_, float idy_, float cx, float cy,
                                           float g, const float* __restrict__ lwr, const float* __restrict__ lbr,
                                           float a2, float b2, float idx2, float idy2, bool wz0) {
    float* hn = h + (size_t)n * 128;
    float hx = hn[lane], hy = hn[HH + lane];
    float xy = hx * hy;
    float z0x = (hx + DTC * (a * hx - b * xy)) * idx_;
    float z0y = (hy + DTC * (b * xy - a * hy)) * idy_;
    float z2x = fmaf(cx, accX, z0x);
    float z2y = fmaf(cy, accY, z0y);
    float nx = fmaf(g, z2x - hx, hx);
    float ny = fmaf(g, z2y - hy, hy);
    float s1 = nx + ny;
    float s2 = fmaf(nx, nx, ny * ny);
#pragma unroll
    for (int m = 1; m < 64; m <<= 1) {
        s1 += __shfl_xor(s1, m, 64);
        s2 += __shfl_xor(s2, m, 64);
    }
    float mean = s1 * (1.0f / 128.0f);
    float var = fmaf(-mean, mean, s2 * (1.0f / 128.0f));
    float rstd = rsqrtf(var + LNEPS);
    float ox = fmaf((nx - mean) * rstd, lwr[lane], lbr[lane]);
    float oy = fmaf((ny - mean) * rstd, lwr[HH + lane], lbr[HH + lane]);
    hn[lane] = ox;
    hn[HH + lane] = oy;
    if (wz0) {
        float xy2 = ox * oy;
        float r2x = ox + DTC * (a2 * ox - b2 * xy2);
        float r2y = oy + DTC * (b2 * xy2 - a2 * oy);
        z0bf8[(size_t)n * HH + lane] = pack_fp8x2(r2x * idx2, r2y * idy2);
    }
}

__global__ __launch_bounds__(256) void k_phase2(float* __restrict__ h,
                                                unsigned short* __restrict__ z0bf8,
                                                const unsigned short* __restrict__ z1bf8,
                                                const int* __restrict__ rp, const uint2* __restrict__ edges,
                                                const float* __restrict__ alpha, const float* __restrict__ beta,
                                                const float* __restrict__ dxp, const float* __restrict__ dyp,
                                                const float* __restrict__ taup,
                                                const float* __restrict__ lnw, const float* __restrict__ lnb,
                                                int l) {
    int lane = threadIdx.x & 63, wid = threadIdx.x >> 6;
    int nA = blockIdx.x * 8 + wid * 2;
    int nB = nA + 1;
    float a = alpha[l], b = beta[l], dx = dxp[l], dy = dyp[l];
    float idx_ = 1.0f / (1.0f + DTC * dx);
    float idy_ = 1.0f / (1.0f + DTC * dy);
    float cx = DTC * dx * idx_, cy = DTC * dy * idy_;
    int e0A = __builtin_amdgcn_readfirstlane(rp[nA]);
    int e1A = __builtin_amdgcn_readfirstlane(rp[nA + 1]);
    int e1B = __builtin_amdgcn_readfirstlane(rp[nA + 2]);
    float aXA = 0.f, aYA = 0.f, aXB = 0.f, aYB = 0.f;
    gather2(z1bf8, edges, e0A, e1A, e1A, e1B, lane * 2, aXA, aYA, aXB, aYB);
    int l2 = (l + 1 < NL) ? l + 1 : l;
    float a2 = alpha[l2], b2 = beta[l2];
    float idx2 = 1.0f / (1.0f + DTC * dxp[l2]);
    float idy2 = 1.0f / (1.0f + DTC * dyp[l2]);
    float g = 1.0f / (1.0f + expf(-taup[l]));
    bool wz0 = (l + 1 < NL);
    const float* lwr = lnw + (size_t)l * 128;
    const float* lbr = lnb + (size_t)l * 128;
    phase2_epi(nA, lane, aXA, aYA, h, z0bf8, a, b, idx_, idy_, cx, cy, g, lwr, lbr, a2, b2, idx2, idy2, wz0);
    phase2_epi(nB, lane, aXB, aYB, h, z0bf8, a, b, idx_, idy_, cx, cy, g, lwr, lbr, a2, b2, idx2, idy2, wz0);
}

// ---------------- output head ----------------

__global__ __launch_bounds__(256) void k_out(const float* __restrict__ h, const float* __restrict__ ow,
                                             const float* __restrict__ ob, const float* __restrict__ lsp,
                                             float* __restrict__ out) {
    __shared__ float hs[64][65];
    __shared__ float ows[NCLS][65];
    __shared__ float obs[NCLS];
    int t = threadIdx.x;
    int n0 = blockIdx.x * 64;
#pragma unroll
    for (int i = 0; i < 16; ++i) {
        int idx = i * 256 + t;
        int r = idx >> 6, c = idx & 63;
        int n = n0 + r;
        hs[r][c] = (n < NN) ? h[(size_t)n * 128 + c] : 0.f;
    }
#pragma unroll
    for (int i = 0; i < 10; ++i) {
        int idx = i * 256 + t;
        int j = idx >> 6, c = idx & 63;
        ows[j][c] = ow[j * HH + c];
    }
    if (t < NCLS) obs[t] = ob[t];
    __syncthreads();
    float ls = lsp[0];
#pragma unroll
    for (int i = 0; i < 10; ++i) {
        int o = i * 256 + t;
        int nl = o / NCLS;
        int j = o - nl * NCLS;
        float acc = 0.f;
#pragma unroll 8
        for (int k = 0; k < HH; ++k) acc = fmaf(hs[nl][k], ows[j][k], acc);
        int n = n0 + nl;
        if (n < NN) out[(size_t)n * NCLS + j] = fmaf(ls, acc, obs[j]);
    }
}

// ---------------- launcher ----------------

extern "C" void kernel_launch(void* const* d_in, const int* in_sizes, int n_in,
                              void* d_out, int out_size, void* d_ws, size_t ws_size,
                              hipStream_t stream) {
    const float* x     = (const float*)d_in[0];
    const int*   ei    = (const int*)d_in[1];
    const float* lw    = (const float*)d_in[2];
    const float* lb    = (const float*)d_in[3];
    const float* alpha = (const float*)d_in[4];
    const float* beta  = (const float*)d_in[5];
    const float* dxp   = (const float*)d_in[6];
    const float* dyp   = (const float*)d_in[7];
    const float* taup  = (const float*)d_in[8];
    const float* lnw   = (const float*)d_in[9];
    const float* lnb   = (const float*)d_in[10];
    const float* ow    = (const float*)d_in[11];
    const float* ob    = (const float*)d_in[12];
    const float* lsp   = (const float*)d_in[13];
    float* out = (float*)d_out;

    const int* srcp = ei;
    const int* dstp = ei + NE;

    char* ws = (char*)d_ws;
    size_t o = 0;
    auto alloc = [&](size_t b) { size_t r = o; o += (b + 255) & ~(size_t)255; return r; };
    int*            row_ptr = (int*)(ws + alloc((NN + 1) * sizeof(int)));
    int*            deg     = (int*)(ws + alloc(NN * sizeof(int)));
    int*            cnt     = (int*)(ws + alloc(NN * sizeof(int)));
    float*          dinv    = (float*)(ws + alloc(NN * sizeof(float)));
    int*            bsum    = (int*)(ws + alloc(256 * sizeof(int)));
    int*            boff    = (int*)(ws + alloc(256 * sizeof(int)));
    uint2*          edges   = (uint2*)(ws + alloc((size_t)NE * sizeof(uint2)));
    float*          hbuf    = (float*)(ws + alloc((size_t)NN * 128 * sizeof(float)));
    unsigned short* z0bf8   = (unsigned short*)(ws + alloc((size_t)NN * HH * sizeof(unsigned short)));
    unsigned short* z1bf8   = (unsigned short*)(ws + alloc((size_t)NN * HH * sizeof(unsigned short)));

    hipMemsetAsync(deg, 0, NN * sizeof(int), stream);
    hipMemsetAsync(cnt, 0, NN * sizeof(int), stream);

    k_deg<<<(NE + 255) / 256, 256, 0, stream>>>(dstp, deg);
    k_scan1<<<NB_SCAN, 256, 0, stream>>>(deg, row_ptr, bsum, dinv);
    k_scan2<<<1, 256, 0, stream>>>(bsum, boff);
    k_scan3<<<NB_SCAN, 256, 0, stream>>>(row_ptr, boff);
    k_scatter<<<(NE + 255) / 256, 256, 0, stream>>>(srcp, dstp, dinv, row_ptr, cnt, edges);

    k_lift<<<NN / LIFT_NPB, 256, 0, stream>>>(x, lw, lb, alpha, beta, dxp, dyp, hbuf, z0bf8);

    for (int l = 0; l < NL; ++l) {
        k_phase1<<<NN / 8, 256, 0, stream>>>(z0bf8, z1bf8, row_ptr, edges, dxp, dyp, l);
        k_phase2<<<NN / 8, 256, 0, stream>>>(hbuf, z0bf8, z1bf8, row_ptr, edges,
                                             alpha, beta, dxp, dyp, taup, lnw, lnb, l);
    }

    k_out<<<(NN + 63) / 64, 256, 0, stream>>>(hbuf, ow, ob, lsp, out);
}

// Round 12
// 981.731 us; speedup vs baseline: 1.4454x; 1.0218x over previous
//
#include <hip/hip_runtime.h>
#include <hip/hip_fp16.h>

#define NN 50000
#define NE 800000
#define CIN 128
#define HH 64
#define NCLS 40
#define NL 15
#define DTC 0.1f
#define LNEPS 1e-5f
#define NB_SCAN 196   // ceil(50000/256)

typedef float f32x2 __attribute__((ext_vector_type(2)));

// ---------------- bf16x2 / fp16x2 / fp8x2 pack-unpack ----------------

__device__ inline unsigned pack_bf2(float x, float y) {
    unsigned ux = __float_as_uint(x);
    unsigned uy = __float_as_uint(y);
    ux = (ux + 0x7fffu + ((ux >> 16) & 1u)) >> 16;   // RNE
    uy = (uy + 0x7fffu + ((uy >> 16) & 1u)) >> 16;
    return ux | (uy << 16);
}
__device__ inline float2 unpack_bf2(unsigned p) {
    float2 r;
    r.x = __uint_as_float(p << 16);
    r.y = __uint_as_float(p & 0xffff0000u);
    return r;
}
// fp16 pair: 10-bit mantissa (8x finer than bf16) — h state is O(1) post-LN.
__device__ inline unsigned pack_h2(float x, float y) {
    __half2 h = __floats2half2_rn(x, y);
    return *reinterpret_cast<unsigned*>(&h);
}
__device__ inline float2 unpack_h2(unsigned p) {
    __half2 h = *reinterpret_cast<__half2*>(&p);
    return __half22float2(h);
}
__device__ inline unsigned short pack_fp8x2(float x, float y) {
    int r = __builtin_amdgcn_cvt_pk_fp8_f32(x, y, 0, false);
    return (unsigned short)(r & 0xffff);
}
__device__ inline float2 unpack_fp8x2(unsigned short p) {
    f32x2 v = __builtin_amdgcn_cvt_pk_f32_fp8((int)(unsigned)p, false);
    float2 r; r.x = v.x; r.y = v.y; return r;
}

// ---------------- degree / normalization precompute ----------------

__global__ __launch_bounds__(256) void k_deg(const int* __restrict__ dst, int* __restrict__ deg) {
    int e = blockIdx.x * 256 + threadIdx.x;
    if (e < NE) atomicAdd(&deg[dst[e]], 1);
}

__global__ __launch_bounds__(256) void k_scan1(const int* __restrict__ deg, int* __restrict__ rp,
                                               int* __restrict__ bsum, float* __restrict__ dinv) {
    int i = blockIdx.x * 256 + threadIdx.x;
    int v = (i < NN) ? deg[i] : 0;
    if (i < NN) dinv[i] = rsqrtf(fmaxf((float)v, 1.0f));
    int lane = threadIdx.x & 63, wid = threadIdx.x >> 6;
    int inc = v;
#pragma unroll
    for (int d = 1; d < 64; d <<= 1) {
        int t = __shfl_up(inc, d, 64);
        if (lane >= d) inc += t;
    }
    __shared__ int wsum[4];
    if (lane == 63) wsum[wid] = inc;
    __syncthreads();
    int woff = 0;
#pragma unroll
    for (int w = 0; w < 4; ++w)
        if (w < wid) woff += wsum[w];
    if (i < NN) rp[i] = woff + inc - v;
    if (threadIdx.x == 255) bsum[blockIdx.x] = woff + inc;
}

__global__ __launch_bounds__(256) void k_scan2(const int* __restrict__ bsum, int* __restrict__ boff) {
    int t = threadIdx.x;
    int v = (t < NB_SCAN) ? bsum[t] : 0;
    int lane = t & 63, wid = t >> 6;
    int inc = v;
#pragma unroll
    for (int d = 1; d < 64; d <<= 1) {
        int tt = __shfl_up(inc, d, 64);
        if (lane >= d) inc += tt;
    }
    __shared__ int wsum[4];
    if (lane == 63) wsum[wid] = inc;
    __syncthreads();
    int woff = 0;
#pragma unroll
    for (int w = 0; w < 4; ++w)
        if (w < wid) woff += wsum[w];
    boff[t] = woff + inc - v;
}

__global__ __launch_bounds__(256) void k_scan3(int* __restrict__ rp, const int* __restrict__ boff) {
    int i = blockIdx.x * 256 + threadIdx.x;
    if (i < NN) rp[i] += boff[i >> 8];
    else if (i == NN) rp[NN] = NE;
}

// edge record: {src*128 byte-offset into fp8 row buffers, ewt bits} -> one 8B store
__global__ __launch_bounds__(256) void k_scatter(const int* __restrict__ src, const int* __restrict__ dst,
                                                 const float* __restrict__ dinv, const int* __restrict__ rp,
                                                 int* __restrict__ cnt, uint2* __restrict__ edges) {
    int e = blockIdx.x * 256 + threadIdx.x;
    if (e >= NE) return;
    int s = src[e], d = dst[e];
    int pos = rp[d] + atomicAdd(&cnt[d], 1);
    uint2 rec;
    rec.x = (unsigned)s * 128u;           // byte offset of row s (64 ch * 2B)
    rec.y = __float_as_uint(dinv[s] * dinv[d]);
    edges[pos] = rec;
}

// ---------------- lift: h = [tanh(x @ lift_w^T + b), ones]; packed h + layer-0 z0 ----

#define LIFT_NPB 16

__global__ __launch_bounds__(256) void k_lift(const float* __restrict__ x, const float* __restrict__ lw,
                                              const float* __restrict__ lb,
                                              const float* __restrict__ alpha, const float* __restrict__ beta,
                                              const float* __restrict__ dxp, const float* __restrict__ dyp,
                                              unsigned* __restrict__ hpk, unsigned short* __restrict__ z0bf8) {
    __shared__ unsigned Wt2[CIN / 2][HH + 1];
    __shared__ float xs[LIFT_NPB][CIN];
    int t = threadIdx.x;
    for (int idx = t; idx < (CIN / 2) * HH; idx += 256) {
        int c = idx & 63, kk = idx >> 6;
        Wt2[kk][c] = pack_bf2(lw[c * CIN + 2 * kk], lw[c * CIN + 2 * kk + 1]);
    }
    int n0 = blockIdx.x * LIFT_NPB;
#pragma unroll
    for (int i = 0; i < LIFT_NPB * CIN / 256; ++i) {
        int idx = i * 256 + t;
        int r = idx >> 7, c = idx & 127;
        xs[r][c] = x[(size_t)(n0 + r) * CIN + c];
    }
    __syncthreads();
    int lane = t & 63, wid = t >> 6;
    float bias = lb[lane];
    float a = alpha[0], b = beta[0];
    float idx0 = 1.0f / (1.0f + DTC * dxp[0]);
    float idy0 = 1.0f / (1.0f + DTC * dyp[0]);
    const float2* x0 = (const float2*)&xs[wid * 4 + 0][0];
    const float2* x1 = (const float2*)&xs[wid * 4 + 1][0];
    const float2* x2 = (const float2*)&xs[wid * 4 + 2][0];
    const float2* x3 = (const float2*)&xs[wid * 4 + 3][0];
    float ac0 = 0.f, ac1 = 0.f, ac2 = 0.f, ac3 = 0.f;
#pragma unroll 8
    for (int kk = 0; kk < CIN / 2; ++kk) {
        float2 wv = unpack_bf2(Wt2[kk][lane]);
        float2 v0 = x0[kk], v1 = x1[kk], v2 = x2[kk], v3 = x3[kk];
        ac0 = fmaf(v0.y, wv.y, fmaf(v0.x, wv.x, ac0));
        ac1 = fmaf(v1.y, wv.y, fmaf(v1.x, wv.x, ac1));
        ac2 = fmaf(v2.y, wv.y, fmaf(v2.x, wv.x, ac2));
        ac3 = fmaf(v3.y, wv.y, fmaf(v3.x, wv.x, ac3));
    }
#pragma unroll
    for (int i = 0; i < 4; ++i) {
        float acc = i == 0 ? ac0 : i == 1 ? ac1 : i == 2 ? ac2 : ac3;
        float hx = tanhf(bias + acc);
        int n = n0 + wid * 4 + i;
        hpk[(size_t)n * HH + lane] = pack_h2(hx, 1.0f);
        // layer-0 z0 = rhs/diag with (X,Y)=(hx,1): xy = hx
        float rx = hx + DTC * (a * hx - b * hx);
        float ry = 1.0f + DTC * (b * hx - a);
        z0bf8[(size_t)n * HH + lane] = pack_fp8x2(rx * idx0, ry * idy0);
    }
}

// ---------------- gather core ----------------
// e ranges are wave-uniform SGPR values (readfirstlane'd) so uint4 edge-record
// loads become scalar (SMEM) loads, off the VMEM path.

__device__ __forceinline__ void batch8(const char* __restrict__ base, const uint2* __restrict__ edges,
                                       int e, int lane2, float& accX, float& accY) {
    uint4 q0 = *(const uint4*)(edges + e);
    uint4 q1 = *(const uint4*)(edges + e + 2);
    uint4 q2 = *(const uint4*)(edges + e + 4);
    uint4 q3 = *(const uint4*)(edges + e + 6);
    unsigned short g0 = *(const unsigned short*)(base + q0.x + lane2);
    unsigned short g1 = *(const unsigned short*)(base + q0.z + lane2);
    unsigned short g2 = *(const unsigned short*)(base + q1.x + lane2);
    unsigned short g3 = *(const unsigned short*)(base + q1.z + lane2);
    unsigned short g4 = *(const unsigned short*)(base + q2.x + lane2);
    unsigned short g5 = *(const unsigned short*)(base + q2.z + lane2);
    unsigned short g6 = *(const unsigned short*)(base + q3.x + lane2);
    unsigned short g7 = *(const unsigned short*)(base + q3.z + lane2);
    float2 v;
    v = unpack_fp8x2(g0); accX = fmaf(__uint_as_float(q0.y), v.x, accX); accY = fmaf(__uint_as_float(q0.y), v.y, accY);
    v = unpack_fp8x2(g1); accX = fmaf(__uint_as_float(q0.w), v.x, accX); accY = fmaf(__uint_as_float(q0.w), v.y, accY);
    v = unpack_fp8x2(g2); accX = fmaf(__uint_as_float(q1.y), v.x, accX); accY = fmaf(__uint_as_float(q1.y), v.y, accY);
    v = unpack_fp8x2(g3); accX = fmaf(__uint_as_float(q1.w), v.x, accX); accY = fmaf(__uint_as_float(q1.w), v.y, accY);
    v = unpack_fp8x2(g4); accX = fmaf(__uint_as_float(q2.y), v.x, accX); accY = fmaf(__uint_as_float(q2.y), v.y, accY);
    v = unpack_fp8x2(g5); accX = fmaf(__uint_as_float(q2.w), v.x, accX); accY = fmaf(__uint_as_float(q2.w), v.y, accY);
    v = unpack_fp8x2(g6); accX = fmaf(__uint_as_float(q3.y), v.x, accX); accY = fmaf(__uint_as_float(q3.y), v.y, accY);
    v = unpack_fp8x2(g7); accX = fmaf(__uint_as_float(q3.w), v.x, accX); accY = fmaf(__uint_as_float(q3.w), v.y, accY);
}

__device__ __forceinline__ void edge_one(const char* __restrict__ base, const uint2* __restrict__ edges,
                                         int e, int lane2, float& accX, float& accY) {
    uint2 ed = edges[e];
    float w = __uint_as_float(ed.y);
    float2 v = unpack_fp8x2(*(const unsigned short*)(base + ed.x + lane2));
    accX = fmaf(w, v.x, accX);
    accY = fmaf(w, v.y, accY);
}

// two independent rolling gather streams (nodes A and B) -> 2x memory parallelism
__device__ __forceinline__ void gather2(const unsigned short* __restrict__ srcbuf,
                                        const uint2* __restrict__ edges,
                                        int e0A, int e1A, int e0B, int e1B, int lane2,
                                        float& aXA, float& aYA, float& aXB, float& aYB) {
    const char* base = (const char*)srcbuf;
    int eA = e0A, eB = e0B;
    if ((eA & 1) && eA < e1A) { edge_one(base, edges, eA, lane2, aXA, aYA); ++eA; }
    if ((eB & 1) && eB < e1B) { edge_one(base, edges, eB, lane2, aXB, aYB); ++eB; }
    while (eA + 8 <= e1A && eB + 8 <= e1B) {
        batch8(base, edges, eA, lane2, aXA, aYA); eA += 8;
        batch8(base, edges, eB, lane2, aXB, aYB); eB += 8;
    }
    while (eA + 8 <= e1A) { batch8(base, edges, eA, lane2, aXA, aYA); eA += 8; }
    while (eB + 8 <= e1B) { batch8(base, edges, eB, lane2, aXB, aYB); eB += 8; }
    for (; eA < e1A; ++eA) edge_one(base, edges, eA, lane2, aXA, aYA);
    for (; eB < e1B; ++eB) edge_one(base, edges, eB, lane2, aXB, aYB);
}

// ---------------- phase kernels (2 nodes per wave) ----------------
// phase1: z1 = z0_own(fp8) + c*(S.z0) — no h access at all.

__global__ __launch_bounds__(256) void k_phase1(const unsigned short* __restrict__ z0bf8,
                                                unsigned short* __restrict__ z1bf8,
                                                const int* __restrict__ rp, const uint2* __restrict__ edges,
                                                const float* __restrict__ dxp, const float* __restrict__ dyp,
                                                int l) {
    int lane = threadIdx.x & 63, wid = threadIdx.x >> 6;
    int nA = blockIdx.x * 8 + wid * 2;       // grid = NN/8 = 6250
    int nB = nA + 1;
    float dx = dxp[l], dy = dyp[l];
    float cx = DTC * dx / (1.0f + DTC * dx);
    float cy = DTC * dy / (1.0f + DTC * dy);
    int e0A = __builtin_amdgcn_readfirstlane(rp[nA]);
    int e1A = __builtin_amdgcn_readfirstlane(rp[nA + 1]);
    int e1B = __builtin_amdgcn_readfirstlane(rp[nA + 2]);
    float aXA = 0.f, aYA = 0.f, aXB = 0.f, aYB = 0.f;
    gather2(z0bf8, edges, e0A, e1A, e1A, e1B, lane * 2, aXA, aYA, aXB, aYB);
    float2 zA = unpack_fp8x2(z0bf8[(size_t)nA * HH + lane]);
    float2 zB = unpack_fp8x2(z0bf8[(size_t)nB * HH + lane]);
    z1bf8[(size_t)nA * HH + lane] = pack_fp8x2(fmaf(cx, aXA, zA.x), fmaf(cy, aYA, zA.y));
    z1bf8[(size_t)nB * HH + lane] = pack_fp8x2(fmaf(cx, aXB, zB.x), fmaf(cy, aYB, zB.y));
}

// phase2: z2 = z0_own(recomputed from fp16 h) + c*(S.z1); gate + LN; packed h update.

__device__ __forceinline__ void phase2_epi(int n, int lane, float accX, float accY,
                                           unsigned* __restrict__ hpk, unsigned short* __restrict__ z0bf8,
                                           float a, float b, float idx_, float idy_, float cx, float cy,
                                           float g, const float* __restrict__ lwr, const float* __restrict__ lbr,
                                           float a2, float b2, float idx2, float idy2, bool wz0) {
    unsigned* hp = hpk + (size_t)n * HH + lane;
    float2 hv = unpack_h2(*hp);
    float hx = hv.x, hy = hv.y;
    float xy = hx * hy;
    float z0x = (hx + DTC * (a * hx - b * xy)) * idx_;
    float z0y = (hy + DTC * (b * xy - a * hy)) * idy_;
    float z2x = fmaf(cx, accX, z0x);
    float z2y = fmaf(cy, accY, z0y);
    float nx = fmaf(g, z2x - hx, hx);
    float ny = fmaf(g, z2y - hy, hy);
    float s1 = nx + ny;
    float s2 = fmaf(nx, nx, ny * ny);
#pragma unroll
    for (int m = 1; m < 64; m <<= 1) {
        s1 += __shfl_xor(s1, m, 64);
        s2 += __shfl_xor(s2, m, 64);
    }
    float mean = s1 * (1.0f / 128.0f);
    float var = fmaf(-mean, mean, s2 * (1.0f / 128.0f));
    float rstd = rsqrtf(var + LNEPS);
    float ox = fmaf((nx - mean) * rstd, lwr[lane], lbr[lane]);
    float oy = fmaf((ny - mean) * rstd, lwr[HH + lane], lbr[HH + lane]);
    *hp = pack_h2(ox, oy);
    if (wz0) {
        float xy2 = ox * oy;
        float r2x = ox + DTC * (a2 * ox - b2 * xy2);
        float r2y = oy + DTC * (b2 * xy2 - a2 * oy);
        z0bf8[(size_t)n * HH + lane] = pack_fp8x2(r2x * idx2, r2y * idy2);
    }
}

__global__ __launch_bounds__(256) void k_phase2(unsigned* __restrict__ hpk,
                                                unsigned short* __restrict__ z0bf8,
                                                const unsigned short* __restrict__ z1bf8,
                                                const int* __restrict__ rp, const uint2* __restrict__ edges,
                                                const float* __restrict__ alpha, const float* __restrict__ beta,
                                                const float* __restrict__ dxp, const float* __restrict__ dyp,
                                                const float* __restrict__ taup,
                                                const float* __restrict__ lnw, const float* __restrict__ lnb,
                                                int l) {
    int lane = threadIdx.x & 63, wid = threadIdx.x >> 6;
    int nA = blockIdx.x * 8 + wid * 2;
    int nB = nA + 1;
    float a = alpha[l], b = beta[l], dx = dxp[l], dy = dyp[l];
    float idx_ = 1.0f / (1.0f + DTC * dx);
    float idy_ = 1.0f / (1.0f + DTC * dy);
    float cx = DTC * dx * idx_, cy = DTC * dy * idy_;
    int e0A = __builtin_amdgcn_readfirstlane(rp[nA]);
    int e1A = __builtin_amdgcn_readfirstlane(rp[nA + 1]);
    int e1B = __builtin_amdgcn_readfirstlane(rp[nA + 2]);
    float aXA = 0.f, aYA = 0.f, aXB = 0.f, aYB = 0.f;
    gather2(z1bf8, edges, e0A, e1A, e1A, e1B, lane * 2, aXA, aYA, aXB, aYB);
    int l2 = (l + 1 < NL) ? l + 1 : l;
    float a2 = alpha[l2], b2 = beta[l2];
    float idx2 = 1.0f / (1.0f + DTC * dxp[l2]);
    float idy2 = 1.0f / (1.0f + DTC * dyp[l2]);
    float g = 1.0f / (1.0f + expf(-taup[l]));
    bool wz0 = (l + 1 < NL);
    const float* lwr = lnw + (size_t)l * 128;
    const float* lbr = lnb + (size_t)l * 128;
    phase2_epi(nA, lane, aXA, aYA, hpk, z0bf8, a, b, idx_, idy_, cx, cy, g, lwr, lbr, a2, b2, idx2, idy2, wz0);
    phase2_epi(nB, lane, aXB, aYB, hpk, z0bf8, a, b, idx_, idy_, cx, cy, g, lwr, lbr, a2, b2, idx2, idy2, wz0);
}

// ---------------- output head (reads packed h, X half) ----------------

__global__ __launch_bounds__(256) void k_out(const unsigned* __restrict__ hpk, const float* __restrict__ ow,
                                             const float* __restrict__ ob, const float* __restrict__ lsp,
                                             float* __restrict__ out) {
    __shared__ float hs[64][65];
    __shared__ float ows[NCLS][65];
    __shared__ float obs[NCLS];
    int t = threadIdx.x;
    int n0 = blockIdx.x * 64;
#pragma unroll
    for (int i = 0; i < 16; ++i) {
        int idx = i * 256 + t;
        int r = idx >> 6, c = idx & 63;
        int n = n0 + r;
        hs[r][c] = (n < NN) ? unpack_h2(hpk[(size_t)n * HH + c]).x : 0.f;
    }
#pragma unroll
    for (int i = 0; i < 10; ++i) {
        int idx = i * 256 + t;
        int j = idx >> 6, c = idx & 63;
        ows[j][c] = ow[j * HH + c];
    }
    if (t < NCLS) obs[t] = ob[t];
    __syncthreads();
    float ls = lsp[0];
#pragma unroll
    for (int i = 0; i < 10; ++i) {
        int o = i * 256 + t;
        int nl = o / NCLS;
        int j = o - nl * NCLS;
        float acc = 0.f;
#pragma unroll 8
        for (int k = 0; k < HH; ++k) acc = fmaf(hs[nl][k], ows[j][k], acc);
        int n = n0 + nl;
        if (n < NN) out[(size_t)n * NCLS + j] = fmaf(ls, acc, obs[j]);
    }
}

// ---------------- launcher ----------------

extern "C" void kernel_launch(void* const* d_in, const int* in_sizes, int n_in,
                              void* d_out, int out_size, void* d_ws, size_t ws_size,
                              hipStream_t stream) {
    const float* x     = (const float*)d_in[0];
    const int*   ei    = (const int*)d_in[1];
    const float* lw    = (const float*)d_in[2];
    const float* lb    = (const float*)d_in[3];
    const float* alpha = (const float*)d_in[4];
    const float* beta  = (const float*)d_in[5];
    const float* dxp   = (const float*)d_in[6];
    const float* dyp   = (const float*)d_in[7];
    const float* taup  = (const float*)d_in[8];
    const float* lnw   = (const float*)d_in[9];
    const float* lnb   = (const float*)d_in[10];
    const float* ow    = (const float*)d_in[11];
    const float* ob    = (const float*)d_in[12];
    const float* lsp   = (const float*)d_in[13];
    float* out = (float*)d_out;

    const int* srcp = ei;
    const int* dstp = ei + NE;

    char* ws = (char*)d_ws;
    size_t o = 0;
    auto alloc = [&](size_t b) { size_t r = o; o += (b + 255) & ~(size_t)255; return r; };
    int*            row_ptr = (int*)(ws + alloc((NN + 1) * sizeof(int)));
    int*            deg     = (int*)(ws + alloc(NN * sizeof(int)));
    int*            cnt     = (int*)(ws + alloc(NN * sizeof(int)));
    float*          dinv    = (float*)(ws + alloc(NN * sizeof(float)));
    int*            bsum    = (int*)(ws + alloc(256 * sizeof(int)));
    int*            boff    = (int*)(ws + alloc(256 * sizeof(int)));
    uint2*          edges   = (uint2*)(ws + alloc((size_t)NE * sizeof(uint2)));
    unsigned*       hpk     = (unsigned*)(ws + alloc((size_t)NN * HH * sizeof(unsigned)));
    unsigned short* z0bf8   = (unsigned short*)(ws + alloc((size_t)NN * HH * sizeof(unsigned short)));
    unsigned short* z1bf8   = (unsigned short*)(ws + alloc((size_t)NN * HH * sizeof(unsigned short)));

    hipMemsetAsync(deg, 0, NN * sizeof(int), stream);
    hipMemsetAsync(cnt, 0, NN * sizeof(int), stream);

    k_deg<<<(NE + 255) / 256, 256, 0, stream>>>(dstp, deg);
    k_scan1<<<NB_SCAN, 256, 0, stream>>>(deg, row_ptr, bsum, dinv);
    k_scan2<<<1, 256, 0, stream>>>(bsum, boff);
    k_scan3<<<NB_SCAN, 256, 0, stream>>>(row_ptr, boff);
    k_scatter<<<(NE + 255) / 256, 256, 0, stream>>>(srcp, dstp, dinv, row_ptr, cnt, edges);

    k_lift<<<NN / LIFT_NPB, 256, 0, stream>>>(x, lw, lb, alpha, beta, dxp, dyp, hpk, z0bf8);

    for (int l = 0; l < NL; ++l) {
        k_phase1<<<NN / 8, 256, 0, stream>>>(z0bf8, z1bf8, row_ptr, edges, dxp, dyp, l);
        k_phase2<<<NN / 8, 256, 0, stream>>>(hpk, z0bf8, z1bf8, row_ptr, edges,
                                             alpha, beta, dxp, dyp, taup, lnw, lnb, l);
    }

    k_out<<<(NN + 63) / 64, 256, 0, stream>>>(hpk, ow, ob, lsp, out);
}

// Round 13
// 977.073 us; speedup vs baseline: 1.4523x; 1.0048x over previous
//
#include <hip/hip_runtime.h>
#include <hip/hip_fp16.h>

#define NN 50000
#define NE 800000
#define CIN 128
#define HH 64
#define NCLS 40
#define NL 15
#define DTC 0.1f
#define LNEPS 1e-5f
#define NB_SCAN 196   // ceil(50000/256)

typedef float f32x2 __attribute__((ext_vector_type(2)));

// ---------------- bf16x2 / fp16x2 / fp8x2 pack-unpack ----------------

__device__ inline unsigned pack_bf2(float x, float y) {
    unsigned ux = __float_as_uint(x);
    unsigned uy = __float_as_uint(y);
    ux = (ux + 0x7fffu + ((ux >> 16) & 1u)) >> 16;   // RNE
    uy = (uy + 0x7fffu + ((uy >> 16) & 1u)) >> 16;
    return ux | (uy << 16);
}
__device__ inline float2 unpack_bf2(unsigned p) {
    float2 r;
    r.x = __uint_as_float(p << 16);
    r.y = __uint_as_float(p & 0xffff0000u);
    return r;
}
__device__ inline unsigned pack_h2(float x, float y) {
    __half2 h = __floats2half2_rn(x, y);
    return *reinterpret_cast<unsigned*>(&h);
}
__device__ inline float2 unpack_h2(unsigned p) {
    __half2 h = *reinterpret_cast<__half2*>(&p);
    return __half22float2(h);
}
__device__ inline unsigned short pack_fp8x2(float x, float y) {
    int r = __builtin_amdgcn_cvt_pk_fp8_f32(x, y, 0, false);
    return (unsigned short)(r & 0xffff);
}
__device__ inline float2 unpack_fp8x2(unsigned short p) {
    f32x2 v = __builtin_amdgcn_cvt_pk_f32_fp8((int)(unsigned)p, false);
    float2 r; r.x = v.x; r.y = v.y; return r;
}

// ---------------- degree / normalization precompute ----------------

__global__ __launch_bounds__(256) void k_deg(const int* __restrict__ dst, int* __restrict__ deg) {
    int e = blockIdx.x * 256 + threadIdx.x;
    if (e < NE) atomicAdd(&deg[dst[e]], 1);
}

__global__ __launch_bounds__(256) void k_scan1(const int* __restrict__ deg, int* __restrict__ rp,
                                               int* __restrict__ bsum, float* __restrict__ dinv) {
    int i = blockIdx.x * 256 + threadIdx.x;
    int v = (i < NN) ? deg[i] : 0;
    if (i < NN) dinv[i] = rsqrtf(fmaxf((float)v, 1.0f));
    int lane = threadIdx.x & 63, wid = threadIdx.x >> 6;
    int inc = v;
#pragma unroll
    for (int d = 1; d < 64; d <<= 1) {
        int t = __shfl_up(inc, d, 64);
        if (lane >= d) inc += t;
    }
    __shared__ int wsum[4];
    if (lane == 63) wsum[wid] = inc;
    __syncthreads();
    int woff = 0;
#pragma unroll
    for (int w = 0; w < 4; ++w)
        if (w < wid) woff += wsum[w];
    if (i < NN) rp[i] = woff + inc - v;
    if (threadIdx.x == 255) bsum[blockIdx.x] = woff + inc;
}

__global__ __launch_bounds__(256) void k_scan2(const int* __restrict__ bsum, int* __restrict__ boff) {
    int t = threadIdx.x;
    int v = (t < NB_SCAN) ? bsum[t] : 0;
    int lane = t & 63, wid = t >> 6;
    int inc = v;
#pragma unroll
    for (int d = 1; d < 64; d <<= 1) {
        int tt = __shfl_up(inc, d, 64);
        if (lane >= d) inc += tt;
    }
    __shared__ int wsum[4];
    if (lane == 63) wsum[wid] = inc;
    __syncthreads();
    int woff = 0;
#pragma unroll
    for (int w = 0; w < 4; ++w)
        if (w < wid) woff += wsum[w];
    boff[t] = woff + inc - v;
}

__global__ __launch_bounds__(256) void k_scan3(int* __restrict__ rp, const int* __restrict__ boff) {
    int i = blockIdx.x * 256 + threadIdx.x;
    if (i < NN) rp[i] += boff[i >> 8];
    else if (i == NN) rp[NN] = NE;
}

// edge record: {src*128 byte-offset into fp8 row buffers, ewt bits} -> one 8B store
__global__ __launch_bounds__(256) void k_scatter(const int* __restrict__ src, const int* __restrict__ dst,
                                                 const float* __restrict__ dinv, const int* __restrict__ rp,
                                                 int* __restrict__ cnt, uint2* __restrict__ edges) {
    int e = blockIdx.x * 256 + threadIdx.x;
    if (e >= NE) return;
    int s = src[e], d = dst[e];
    int pos = rp[d] + atomicAdd(&cnt[d], 1);
    uint2 rec;
    rec.x = (unsigned)s * 128u;           // byte offset of row s (64 ch * 2B)
    rec.y = __float_as_uint(dinv[s] * dinv[d]);
    edges[pos] = rec;
}

// ---------------- lift: h = [tanh(x @ lift_w^T + b), ones]; packed h + layer-0 z0 ----

#define LIFT_NPB 16

__global__ __launch_bounds__(256) void k_lift(const float* __restrict__ x, const float* __restrict__ lw,
                                              const float* __restrict__ lb,
                                              const float* __restrict__ alpha, const float* __restrict__ beta,
                                              const float* __restrict__ dxp, const float* __restrict__ dyp,
                                              unsigned* __restrict__ hpk, unsigned short* __restrict__ z0bf8) {
    __shared__ unsigned Wt2[CIN / 2][HH + 1];
    __shared__ float xs[LIFT_NPB][CIN];
    int t = threadIdx.x;
    for (int idx = t; idx < (CIN / 2) * HH; idx += 256) {
        int c = idx & 63, kk = idx >> 6;
        Wt2[kk][c] = pack_bf2(lw[c * CIN + 2 * kk], lw[c * CIN + 2 * kk + 1]);
    }
    int n0 = blockIdx.x * LIFT_NPB;
#pragma unroll
    for (int i = 0; i < LIFT_NPB * CIN / 256; ++i) {
        int idx = i * 256 + t;
        int r = idx >> 7, c = idx & 127;
        xs[r][c] = x[(size_t)(n0 + r) * CIN + c];
    }
    __syncthreads();
    int lane = t & 63, wid = t >> 6;
    float bias = lb[lane];
    float a = alpha[0], b = beta[0];
    float idx0 = 1.0f / (1.0f + DTC * dxp[0]);
    float idy0 = 1.0f / (1.0f + DTC * dyp[0]);
    const float2* x0 = (const float2*)&xs[wid * 4 + 0][0];
    const float2* x1 = (const float2*)&xs[wid * 4 + 1][0];
    const float2* x2 = (const float2*)&xs[wid * 4 + 2][0];
    const float2* x3 = (const float2*)&xs[wid * 4 + 3][0];
    float ac0 = 0.f, ac1 = 0.f, ac2 = 0.f, ac3 = 0.f;
#pragma unroll 8
    for (int kk = 0; kk < CIN / 2; ++kk) {
        float2 wv = unpack_bf2(Wt2[kk][lane]);
        float2 v0 = x0[kk], v1 = x1[kk], v2 = x2[kk], v3 = x3[kk];
        ac0 = fmaf(v0.y, wv.y, fmaf(v0.x, wv.x, ac0));
        ac1 = fmaf(v1.y, wv.y, fmaf(v1.x, wv.x, ac1));
        ac2 = fmaf(v2.y, wv.y, fmaf(v2.x, wv.x, ac2));
        ac3 = fmaf(v3.y, wv.y, fmaf(v3.x, wv.x, ac3));
    }
#pragma unroll
    for (int i = 0; i < 4; ++i) {
        float acc = i == 0 ? ac0 : i == 1 ? ac1 : i == 2 ? ac2 : ac3;
        float hx = tanhf(bias + acc);
        int n = n0 + wid * 4 + i;
        hpk[(size_t)n * HH + lane] = pack_h2(hx, 1.0f);
        float rx = hx + DTC * (a * hx - b * hx);
        float ry = 1.0f + DTC * (b * hx - a);
        z0bf8[(size_t)n * HH + lane] = pack_fp8x2(rx * idx0, ry * idy0);
    }
}

// ---------------- gather core ----------------
// Edge-range bounds are wave-uniform SGPRs (readfirstlane'd) so uint4 edge
// record loads are scalar (SMEM). batchAB issues ALL 16 gathers (two streams)
// before consuming any -> ~16 outstanding VMEM loads per wave.

#define GLOAD(g, q, comp) unsigned short g = *(const unsigned short*)(base + q.comp + lane2)
#define CONS(g, q, wcomp, aX, aY)                                      \
    do {                                                               \
        float2 v = unpack_fp8x2(g);                                    \
        float w = __uint_as_float(q.wcomp);                            \
        aX = fmaf(w, v.x, aX);                                         \
        aY = fmaf(w, v.y, aY);                                         \
    } while (0)

__device__ __forceinline__ void batchAB(const char* __restrict__ base, const uint2* __restrict__ edges,
                                        int eA, int eB, int lane2,
                                        float& aXA, float& aYA, float& aXB, float& aYB) {
    uint4 qa0 = *(const uint4*)(edges + eA);
    uint4 qa1 = *(const uint4*)(edges + eA + 2);
    uint4 qa2 = *(const uint4*)(edges + eA + 4);
    uint4 qa3 = *(const uint4*)(edges + eA + 6);
    uint4 qb0 = *(const uint4*)(edges + eB);
    uint4 qb1 = *(const uint4*)(edges + eB + 2);
    uint4 qb2 = *(const uint4*)(edges + eB + 4);
    uint4 qb3 = *(const uint4*)(edges + eB + 6);
    GLOAD(ga0, qa0, x); GLOAD(ga1, qa0, z);
    GLOAD(ga2, qa1, x); GLOAD(ga3, qa1, z);
    GLOAD(ga4, qa2, x); GLOAD(ga5, qa2, z);
    GLOAD(ga6, qa3, x); GLOAD(ga7, qa3, z);
    GLOAD(gb0, qb0, x); GLOAD(gb1, qb0, z);
    GLOAD(gb2, qb1, x); GLOAD(gb3, qb1, z);
    GLOAD(gb4, qb2, x); GLOAD(gb5, qb2, z);
    GLOAD(gb6, qb3, x); GLOAD(gb7, qb3, z);
    CONS(ga0, qa0, y, aXA, aYA); CONS(ga1, qa0, w, aXA, aYA);
    CONS(ga2, qa1, y, aXA, aYA); CONS(ga3, qa1, w, aXA, aYA);
    CONS(ga4, qa2, y, aXA, aYA); CONS(ga5, qa2, w, aXA, aYA);
    CONS(ga6, qa3, y, aXA, aYA); CONS(ga7, qa3, w, aXA, aYA);
    CONS(gb0, qb0, y, aXB, aYB); CONS(gb1, qb0, w, aXB, aYB);
    CONS(gb2, qb1, y, aXB, aYB); CONS(gb3, qb1, w, aXB, aYB);
    CONS(gb4, qb2, y, aXB, aYB); CONS(gb5, qb2, w, aXB, aYB);
    CONS(gb6, qb3, y, aXB, aYB); CONS(gb7, qb3, w, aXB, aYB);
}

__device__ __forceinline__ void batch8(const char* __restrict__ base, const uint2* __restrict__ edges,
                                       int e, int lane2, float& accX, float& accY) {
    uint4 q0 = *(const uint4*)(edges + e);
    uint4 q1 = *(const uint4*)(edges + e + 2);
    uint4 q2 = *(const uint4*)(edges + e + 4);
    uint4 q3 = *(const uint4*)(edges + e + 6);
    GLOAD(g0, q0, x); GLOAD(g1, q0, z);
    GLOAD(g2, q1, x); GLOAD(g3, q1, z);
    GLOAD(g4, q2, x); GLOAD(g5, q2, z);
    GLOAD(g6, q3, x); GLOAD(g7, q3, z);
    CONS(g0, q0, y, accX, accY); CONS(g1, q0, w, accX, accY);
    CONS(g2, q1, y, accX, accY); CONS(g3, q1, w, accX, accY);
    CONS(g4, q2, y, accX, accY); CONS(g5, q2, w, accX, accY);
    CONS(g6, q3, y, accX, accY); CONS(g7, q3, w, accX, accY);
}

__device__ __forceinline__ void edge_one(const char* __restrict__ base, const uint2* __restrict__ edges,
                                         int e, int lane2, float& accX, float& accY) {
    uint2 ed = edges[e];
    float w = __uint_as_float(ed.y);
    float2 v = unpack_fp8x2(*(const unsigned short*)(base + ed.x + lane2));
    accX = fmaf(w, v.x, accX);
    accY = fmaf(w, v.y, accY);
}

__device__ __forceinline__ void gather2(const unsigned short* __restrict__ srcbuf,
                                        const uint2* __restrict__ edges,
                                        int e0A, int e1A, int e0B, int e1B, int lane2,
                                        float& aXA, float& aYA, float& aXB, float& aYB) {
    const char* base = (const char*)srcbuf;
    int eA = e0A, eB = e0B;
    if ((eA & 1) && eA < e1A) { edge_one(base, edges, eA, lane2, aXA, aYA); ++eA; }
    if ((eB & 1) && eB < e1B) { edge_one(base, edges, eB, lane2, aXB, aYB); ++eB; }
    while (eA + 8 <= e1A && eB + 8 <= e1B) {
        batchAB(base, edges, eA, eB, lane2, aXA, aYA, aXB, aYB);
        eA += 8; eB += 8;
    }
    while (eA + 8 <= e1A) { batch8(base, edges, eA, lane2, aXA, aYA); eA += 8; }
    while (eB + 8 <= e1B) { batch8(base, edges, eB, lane2, aXB, aYB); eB += 8; }
    for (; eA < e1A; ++eA) edge_one(base, edges, eA, lane2, aXA, aYA);
    for (; eB < e1B; ++eB) edge_one(base, edges, eB, lane2, aXB, aYB);
}

// ---------------- phase kernels (2 nodes per wave) ----------------
// phase1: z1 = z0_own(fp8) + c*(S.z0) — no h access at all.

__global__ __launch_bounds__(256) void k_phase1(const unsigned short* __restrict__ z0bf8,
                                                unsigned short* __restrict__ z1bf8,
                                                const int* __restrict__ rp, const uint2* __restrict__ edges,
                                                const float* __restrict__ dxp, const float* __restrict__ dyp,
                                                int l) {
    int lane = threadIdx.x & 63, wid = threadIdx.x >> 6;
    int nA = blockIdx.x * 8 + wid * 2;       // grid = NN/8 = 6250
    int nB = nA + 1;
    float dx = dxp[l], dy = dyp[l];
    float cx = DTC * dx / (1.0f + DTC * dx);
    float cy = DTC * dy / (1.0f + DTC * dy);
    int e0A = __builtin_amdgcn_readfirstlane(rp[nA]);
    int e1A = __builtin_amdgcn_readfirstlane(rp[nA + 1]);
    int e1B = __builtin_amdgcn_readfirstlane(rp[nA + 2]);
    float aXA = 0.f, aYA = 0.f, aXB = 0.f, aYB = 0.f;
    gather2(z0bf8, edges, e0A, e1A, e1A, e1B, lane * 2, aXA, aYA, aXB, aYB);
    float2 zA = unpack_fp8x2(z0bf8[(size_t)nA * HH + lane]);
    float2 zB = unpack_fp8x2(z0bf8[(size_t)nB * HH + lane]);
    z1bf8[(size_t)nA * HH + lane] = pack_fp8x2(fmaf(cx, aXA, zA.x), fmaf(cy, aYA, zA.y));
    z1bf8[(size_t)nB * HH + lane] = pack_fp8x2(fmaf(cx, aXB, zB.x), fmaf(cy, aYB, zB.y));
}

// phase2: z2 = z0_own(recomputed from fp16 h) + c*(S.z1); gate + LN; packed h update.

__device__ __forceinline__ void phase2_epi(int n, int lane, float accX, float accY,
                                           unsigned* __restrict__ hpk, unsigned short* __restrict__ z0bf8,
                                           float a, float b, float idx_, float idy_, float cx, float cy,
                                           float g, const float* __restrict__ lwr, const float* __restrict__ lbr,
                                           float a2, float b2, float idx2, float idy2, bool wz0) {
    unsigned* hp = hpk + (size_t)n * HH + lane;
    float2 hv = unpack_h2(*hp);
    float hx = hv.x, hy = hv.y;
    float xy = hx * hy;
    float z0x = (hx + DTC * (a * hx - b * xy)) * idx_;
    float z0y = (hy + DTC * (b * xy - a * hy)) * idy_;
    float z2x = fmaf(cx, accX, z0x);
    float z2y = fmaf(cy, accY, z0y);
    float nx = fmaf(g, z2x - hx, hx);
    float ny = fmaf(g, z2y - hy, hy);
    float s1 = nx + ny;
    float s2 = fmaf(nx, nx, ny * ny);
#pragma unroll
    for (int m = 1; m < 64; m <<= 1) {
        s1 += __shfl_xor(s1, m, 64);
        s2 += __shfl_xor(s2, m, 64);
    }
    float mean = s1 * (1.0f / 128.0f);
    float var = fmaf(-mean, mean, s2 * (1.0f / 128.0f));
    float rstd = rsqrtf(var + LNEPS);
    float ox = fmaf((nx - mean) * rstd, lwr[lane], lbr[lane]);
    float oy = fmaf((ny - mean) * rstd, lwr[HH + lane], lbr[HH + lane]);
    *hp = pack_h2(ox, oy);
    if (wz0) {
        float xy2 = ox * oy;
        float r2x = ox + DTC * (a2 * ox - b2 * xy2);
        float r2y = oy + DTC * (b2 * xy2 - a2 * oy);
        z0bf8[(size_t)n * HH + lane] = pack_fp8x2(r2x * idx2, r2y * idy2);
    }
}

__global__ __launch_bounds__(256) void k_phase2(unsigned* __restrict__ hpk,
                                                unsigned short* __restrict__ z0bf8,
                                                const unsigned short* __restrict__ z1bf8,
                                                const int* __restrict__ rp, const uint2* __restrict__ edges,
                                                const float* __restrict__ alpha, const float* __restrict__ beta,
                                                const float* __restrict__ dxp, const float* __restrict__ dyp,
                                                const float* __restrict__ taup,
                                                const float* __restrict__ lnw, const float* __restrict__ lnb,
                                                int l) {
    int lane = threadIdx.x & 63, wid = threadIdx.x >> 6;
    int nA = blockIdx.x * 8 + wid * 2;
    int nB = nA + 1;
    float a = alpha[l], b = beta[l], dx = dxp[l], dy = dyp[l];
    float idx_ = 1.0f / (1.0f + DTC * dx);
    float idy_ = 1.0f / (1.0f + DTC * dy);
    float cx = DTC * dx * idx_, cy = DTC * dy * idy_;
    int e0A = __builtin_amdgcn_readfirstlane(rp[nA]);
    int e1A = __builtin_amdgcn_readfirstlane(rp[nA + 1]);
    int e1B = __builtin_amdgcn_readfirstlane(rp[nA + 2]);
    float aXA = 0.f, aYA = 0.f, aXB = 0.f, aYB = 0.f;
    gather2(z1bf8, edges, e0A, e1A, e1A, e1B, lane * 2, aXA, aYA, aXB, aYB);
    int l2 = (l + 1 < NL) ? l + 1 : l;
    float a2 = alpha[l2], b2 = beta[l2];
    float idx2 = 1.0f / (1.0f + DTC * dxp[l2]);
    float idy2 = 1.0f / (1.0f + DTC * dyp[l2]);
    float g = 1.0f / (1.0f + expf(-taup[l]));
    bool wz0 = (l + 1 < NL);
    const float* lwr = lnw + (size_t)l * 128;
    const float* lbr = lnb + (size_t)l * 128;
    phase2_epi(nA, lane, aXA, aYA, hpk, z0bf8, a, b, idx_, idy_, cx, cy, g, lwr, lbr, a2, b2, idx2, idy2, wz0);
    phase2_epi(nB, lane, aXB, aYB, hpk, z0bf8, a, b, idx_, idy_, cx, cy, g, lwr, lbr, a2, b2, idx2, idy2, wz0);
}

// ---------------- output head (reads packed h, X half) ----------------

__global__ __launch_bounds__(256) void k_out(const unsigned* __restrict__ hpk, const float* __restrict__ ow,
                                             const float* __restrict__ ob, const float* __restrict__ lsp,
                                             float* __restrict__ out) {
    __shared__ float hs[64][65];
    __shared__ float ows[NCLS][65];
    __shared__ float obs[NCLS];
    int t = threadIdx.x;
    int n0 = blockIdx.x * 64;
#pragma unroll
    for (int i = 0; i < 16; ++i) {
        int idx = i * 256 + t;
        int r = idx >> 6, c = idx & 63;
        int n = n0 + r;
        hs[r][c] = (n < NN) ? unpack_h2(hpk[(size_t)n * HH + c]).x : 0.f;
    }
#pragma unroll
    for (int i = 0; i < 10; ++i) {
        int idx = i * 256 + t;
        int j = idx >> 6, c = idx & 63;
        ows[j][c] = ow[j * HH + c];
    }
    if (t < NCLS) obs[t] = ob[t];
    __syncthreads();
    float ls = lsp[0];
#pragma unroll
    for (int i = 0; i < 10; ++i) {
        int o = i * 256 + t;
        int nl = o / NCLS;
        int j = o - nl * NCLS;
        float acc = 0.f;
#pragma unroll 8
        for (int k = 0; k < HH; ++k) acc = fmaf(hs[nl][k], ows[j][k], acc);
        int n = n0 + nl;
        if (n < NN) out[(size_t)n * NCLS + j] = fmaf(ls, acc, obs[j]);
    }
}

// ---------------- launcher ----------------

extern "C" void kernel_launch(void* const* d_in, const int* in_sizes, int n_in,
                              void* d_out, int out_size, void* d_ws, size_t ws_size,
                              hipStream_t stream) {
    const float* x     = (const float*)d_in[0];
    const int*   ei    = (const int*)d_in[1];
    const float* lw    = (const float*)d_in[2];
    const float* lb    = (const float*)d_in[3];
    const float* alpha = (const float*)d_in[4];
    const float* beta  = (const float*)d_in[5];
    const float* dxp   = (const float*)d_in[6];
    const float* dyp   = (const float*)d_in[7];
    const float* taup  = (const float*)d_in[8];
    const float* lnw   = (const float*)d_in[9];
    const float* lnb   = (const float*)d_in[10];
    const float* ow    = (const float*)d_in[11];
    const float* ob    = (const float*)d_in[12];
    const float* lsp   = (const float*)d_in[13];
    float* out = (float*)d_out;

    const int* srcp = ei;
    const int* dstp = ei + NE;

    char* ws = (char*)d_ws;
    size_t o = 0;
    auto alloc = [&](size_t b) { size_t r = o; o += (b + 255) & ~(size_t)255; return r; };
    int*            row_ptr = (int*)(ws + alloc((NN + 1) * sizeof(int)));
    int*            deg     = (int*)(ws + alloc(NN * sizeof(int)));
    int*            cnt     = (int*)(ws + alloc(NN * sizeof(int)));
    float*          dinv    = (float*)(ws + alloc(NN * sizeof(float)));
    int*            bsum    = (int*)(ws + alloc(256 * sizeof(int)));
    int*            boff    = (int*)(ws + alloc(256 * sizeof(int)));
    uint2*          edges   = (uint2*)(ws + alloc((size_t)NE * sizeof(uint2)));
    unsigned*       hpk     = (unsigned*)(ws + alloc((size_t)NN * HH * sizeof(unsigned)));
    unsigned short* z0bf8   = (unsigned short*)(ws + alloc((size_t)NN * HH * sizeof(unsigned short)));
    unsigned short* z1bf8   = (unsigned short*)(ws + alloc((size_t)NN * HH * sizeof(unsigned short)));

    hipMemsetAsync(deg, 0, NN * sizeof(int), stream);
    hipMemsetAsync(cnt, 0, NN * sizeof(int), stream);

    k_deg<<<(NE + 255) / 256, 256, 0, stream>>>(dstp, deg);
    k_scan1<<<NB_SCAN, 256, 0, stream>>>(deg, row_ptr, bsum, dinv);
    k_scan2<<<1, 256, 0, stream>>>(bsum, boff);
    k_scan3<<<NB_SCAN, 256, 0, stream>>>(row_ptr, boff);
    k_scatter<<<(NE + 255) / 256, 256, 0, stream>>>(srcp, dstp, dinv, row_ptr, cnt, edges);

    k_lift<<<NN / LIFT_NPB, 256, 0, stream>>>(x, lw, lb, alpha, beta, dxp, dyp, hpk, z0bf8);

    for (int l = 0; l < NL; ++l) {
        k_phase1<<<NN / 8, 256, 0, stream>>>(z0bf8, z1bf8, row_ptr, edges, dxp, dyp, l);
        k_phase2<<<NN / 8, 256, 0, stream>>>(hpk, z0bf8, z1bf8, row_ptr, edges,
                                             alpha, beta, dxp, dyp, taup, lnw, lnb, l);
    }

    k_out<<<(NN + 63) / 64, 256, 0, stream>>>(hpk, ow, ob, lsp, out);
}